// Round 3
// baseline (4376.881 us; speedup 1.0000x reference)
//
#include <hip/hip_runtime.h>

#define NN 100000
#define NE 3200000
#define NG 2048
#define DD 256
#define EPSV 1e-5f
#define SCAN_N 100096           // 391 * 256 >= NN+1
#define SCAN_B 391
#define STRIP 12800
#define NSTRIP 8                // ceil(100000 / 12800)
#define GCH 1568                // gram split-K chunk rows (98 * 16)
#define NGCH 64                 // 64 * 1568 >= NN

__device__ __forceinline__ float4 ld4(const float* p) {
    return *reinterpret_cast<const float4*>(p);
}
__device__ __forceinline__ void st4(float* p, float4 v) {
    *reinterpret_cast<float4*>(p) = v;
}

// ---------------- zero fill (graph-capture-safe) ---------------------------
__global__ __launch_bounds__(256) void zero_k(float* __restrict__ p, int n) {
    int i = blockIdx.x * 256 + threadIdx.x;
    if (i < n) p[i] = 0.f;
}

// ---------------- Atom encoder: h[n,:] = sum_c atom_emb[c, x[n,c], :] ------
__global__ __launch_bounds__(256) void atom_embed_k(
    const int* __restrict__ x, const float* __restrict__ emb,
    float* __restrict__ H)
{
    int lane = threadIdx.x & 63;
    int n = blockIdx.x * 4 + (threadIdx.x >> 6);
    if (n >= NN) return;
    int c4 = lane * 4;
    float4 acc = make_float4(0.f, 0.f, 0.f, 0.f);
#pragma unroll
    for (int c = 0; c < 9; ++c) {
        int idx = x[n * 9 + c];
        float4 v = ld4(emb + (size_t)(c * 100 + idx) * DD + c4);
        acc.x += v.x; acc.y += v.y; acc.z += v.z; acc.w += v.w;
    }
    st4(H + (size_t)n * DD + c4, acc);
}

// ---------------- CSR build ------------------------------------------------
__global__ __launch_bounds__(256) void hist_k(const int* __restrict__ ei,
                                              int* __restrict__ cnt)
{
    int e = blockIdx.x * 256 + threadIdx.x;
    if (e < NE) atomicAdd(&cnt[ei[NE + e]], 1);
}

// in-place: cnt[i] -> block-local exclusive prefix; bsum[b] = block total
__global__ __launch_bounds__(256) void scan1_k(int* __restrict__ cnt,
                                               int* __restrict__ bsum)
{
    __shared__ int s[2][256];
    int t = threadIdx.x;
    int i = blockIdx.x * 256 + t;
    int v = cnt[i];
    s[0][t] = v;
    __syncthreads();
    int p = 0;
    for (int off = 1; off < 256; off <<= 1) {
        int xv = s[p][t];
        if (t >= off) xv += s[p][t - off];
        s[p ^ 1][t] = xv;
        p ^= 1;
        __syncthreads();
    }
    int inc = s[p][t];
    cnt[i] = inc - v;
    if (t == 255) bsum[blockIdx.x] = inc;
}

__global__ __launch_bounds__(512) void scan2_k(const int* __restrict__ bsum,
                                               int* __restrict__ boff)
{
    __shared__ int s[2][512];
    int t = threadIdx.x;
    int v = (t < SCAN_B) ? bsum[t] : 0;
    s[0][t] = v;
    __syncthreads();
    int p = 0;
    for (int off = 1; off < 512; off <<= 1) {
        int xv = s[p][t];
        if (t >= off) xv += s[p][t - off];
        s[p ^ 1][t] = xv;
        p ^= 1;
        __syncthreads();
    }
    boff[t] = s[p][t] - v;
}

__global__ __launch_bounds__(256) void scan3_k(const int* __restrict__ cnt,
                                               const int* __restrict__ boff,
                                               int* __restrict__ rs,
                                               int* __restrict__ cursor)
{
    int i = blockIdx.x * 256 + threadIdx.x;
    int v = cnt[i] + boff[blockIdx.x];
    rs[i] = v;
    if (i < NN) cursor[i] = v;
}

__global__ __launch_bounds__(256) void scatter_k(const int* __restrict__ ei,
                                                 int* __restrict__ cursor,
                                                 int* __restrict__ perm)
{
    int e = blockIdx.x * 256 + threadIdx.x;
    if (e >= NE) return;
    int pos = atomicAdd(&cursor[ei[NE + e]], 1);
    perm[pos] = e;
}

// ---------------- Gather-aggregate: Z[n] = H[n] + sum_e relu(H[src]+bond) --
__global__ __launch_bounds__(256) void gather_agg_k(
    const float* __restrict__ H, const int* __restrict__ ei,
    const int* __restrict__ ea, const float* __restrict__ bond,
    const int* __restrict__ rs, const int* __restrict__ perm,
    float* __restrict__ Z)
{
    int lane = threadIdx.x & 63;
    int n = blockIdx.x * 4 + (threadIdx.x >> 6);
    if (n >= NN) return;
    int c4 = lane * 4;
    float4 acc = ld4(H + (size_t)n * DD + c4);       // the "+ h" term
    int lo = rs[n], hi = rs[n + 1];
    for (int t = lo; t < hi; ++t) {
        int e = perm[t];
        int src = ei[e];
        int b0 = ea[e * 3 + 0], b1 = ea[e * 3 + 1], b2 = ea[e * 3 + 2];
        float4 v  = ld4(H + (size_t)src * DD + c4);
        float4 t0 = ld4(bond + (size_t)(b0) * DD + c4);
        float4 t1 = ld4(bond + (size_t)(10 + b1) * DD + c4);
        float4 t2 = ld4(bond + (size_t)(20 + b2) * DD + c4);
        acc.x += fmaxf(v.x + t0.x + t1.x + t2.x, 0.f);
        acc.y += fmaxf(v.y + t0.y + t1.y + t2.y, 0.f);
        acc.z += fmaxf(v.z + t0.z + t1.z + t2.z, 0.f);
        acc.w += fmaxf(v.w + t0.w + t1.w + t2.w, 0.f);
    }
    st4(Z + (size_t)n * DD + c4, acc);
}

// ---------------- Gram: G += Z^T Z (split-K, atomics) ----------------------
// grid = 4 tiles (2x2 of 128x128) x NGCH chunks; 256 threads, 8x8 micro-tile
__global__ __launch_bounds__(256) void gram_k(const float* __restrict__ Z,
                                              float* __restrict__ G)
{
    __shared__ __align__(16) float As[16][132];
    __shared__ __align__(16) float Bs[16][132];
    const int tid = threadIdx.x;
    const int bj = blockIdx.x & 1;
    const int bi = (blockIdx.x >> 1) & 1;
    const int ch = blockIdx.x >> 2;
    const int rbase = ch * GCH;
    const int tx = tid & 15;
    const int ty = tid >> 4;

    float acc[8][8] = {};

    for (int kt = 0; kt < GCH; kt += 16) {
#pragma unroll
        for (int i = 0; i < 2; ++i) {
            int f = i * 256 + tid;
            int kk = f >> 5;
            int cq = f & 31;
            int r = rbase + kt + kk;
            float4 a = make_float4(0.f, 0.f, 0.f, 0.f);
            float4 b = make_float4(0.f, 0.f, 0.f, 0.f);
            if (r < NN) {
                a = ld4(Z + (size_t)r * DD + bi * 128 + cq * 4);
                b = ld4(Z + (size_t)r * DD + bj * 128 + cq * 4);
            }
            st4(&As[kk][cq * 4], a);
            st4(&Bs[kk][cq * 4], b);
        }
        __syncthreads();
#pragma unroll
        for (int kk = 0; kk < 16; ++kk) {
            float4 a0 = *reinterpret_cast<const float4*>(&As[kk][ty * 4]);
            float4 a1 = *reinterpret_cast<const float4*>(&As[kk][64 + ty * 4]);
            float4 b0 = *reinterpret_cast<const float4*>(&Bs[kk][tx * 4]);
            float4 b1 = *reinterpret_cast<const float4*>(&Bs[kk][64 + tx * 4]);
            float av[8] = {a0.x, a0.y, a0.z, a0.w, a1.x, a1.y, a1.z, a1.w};
            float bv[8] = {b0.x, b0.y, b0.z, b0.w, b1.x, b1.y, b1.z, b1.w};
#pragma unroll
            for (int i = 0; i < 8; ++i)
#pragma unroll
                for (int j = 0; j < 8; ++j)
                    acc[i][j] = fmaf(av[i], bv[j], acc[i][j]);
        }
        __syncthreads();
    }
#pragma unroll
    for (int i = 0; i < 8; ++i) {
        int row = bi * 128 + (i >> 2) * 64 + ty * 4 + (i & 3);
#pragma unroll
        for (int j = 0; j < 8; ++j) {
            int col = bj * 128 + (j >> 2) * 64 + tx * 4 + (j & 3);
            atomicAdd(&G[row * 256 + col], acc[i][j]);
        }
    }
}

// ---------------- column sums of Z ----------------------------------------
__global__ __launch_bounds__(256) void colsum_k(const float* __restrict__ Z,
                                                float* __restrict__ cs)
{
    int t = threadIdx.x;
    int r0 = blockIdx.x * 256;
    int r1 = r0 + 256 < NN ? r0 + 256 : NN;
    float acc = 0.f;
    for (int r = r0; r < r1; ++r) acc += Z[(size_t)r * DD + t];
    atomicAdd(&cs[t], acc);
}

// ---------------- BN prep from Gram: scale/shift per output column ---------
// y = zW + b; S1 = cs@w + N b; S2 = w^T G w + 2b(cs@w) + N b^2
__global__ __launch_bounds__(256) void bnprep_k(
    const float* __restrict__ G, const float* __restrict__ cs,
    const float* __restrict__ W, const float* __restrict__ b,
    const float* __restrict__ g, const float* __restrict__ be,
    float* __restrict__ scl, float* __restrict__ shf, int N)
{
    __shared__ float wv[256];
    __shared__ float r1[256];
    __shared__ float r2[256];
    int c = blockIdx.x;
    int t = threadIdx.x;
    wv[t] = W[t * N + c];
    __syncthreads();
    float gd = 0.f;
    const float* Gr = G + t * 256;
    for (int j = 0; j < 256; ++j) gd = fmaf(Gr[j], wv[j], gd);
    r1[t] = wv[t] * gd;
    r2[t] = cs[t] * wv[t];
    __syncthreads();
    for (int off = 128; off > 0; off >>= 1) {
        if (t < off) { r1[t] += r1[t + off]; r2[t] += r2[t + off]; }
        __syncthreads();
    }
    if (t == 0) {
        float szw = r2[0];            // sum over rows of (zW)_c
        float s2zw = r1[0];           // sum over rows of (zW)_c^2
        float bb = b[c];
        float fN = (float)NN;
        float S1 = szw + fN * bb;
        float S2 = s2zw + 2.f * bb * szw + fN * bb * bb;
        float mu = S1 / fN;
        float var = S2 / fN - mu * mu;
        float s = g[c] * rsqrtf(var + EPSV);
        scl[c] = s;
        shf[c] = be[c] - mu * s;
    }
}

// ---------------- Tiled f32 GEMM: C = A @ W + bias, fused epilogue ---------
// BM=BN=128, BK=16, 256 threads, 8x8 micro-tile (2x2 blocks of 4x4).
// OUTM=1: relu(y);  OUTM=2: relu(y*scl + shf)  (BN folded)
#define BM 128
#define BN 128
#define BK 16

template <int OUTM>
__global__ __launch_bounds__(256) void gemm_k(
    const float* __restrict__ A, const float* __restrict__ W,
    const float* __restrict__ bias, float* __restrict__ C,
    int M, int N, int K,
    const float* __restrict__ scl, const float* __restrict__ shf)
{
    __shared__ __align__(16) float As[BK][BM + 4];
    __shared__ __align__(16) float Bs[BK][BN + 4];

    const int tid = threadIdx.x;
    const int ntx = N / BN;
    const int bx = blockIdx.x % ntx;
    const int by = blockIdx.x / ntx;
    const int tx = tid & 15;
    const int ty = tid >> 4;
    const int row0 = by * BM;
    const int col0 = bx * BN;

    float acc[8][8] = {};

    for (int kt = 0; kt < K; kt += BK) {
#pragma unroll
        for (int i = 0; i < 2; ++i) {
            int f = i * 256 + tid;
            int row = f >> 2;
            int q = f & 3;
            int r = row0 + row;
            if (r >= M) r = M - 1;
            float4 a = ld4(A + (size_t)r * K + kt + q * 4);
            As[q * 4 + 0][row] = a.x;
            As[q * 4 + 1][row] = a.y;
            As[q * 4 + 2][row] = a.z;
            As[q * 4 + 3][row] = a.w;
        }
#pragma unroll
        for (int i = 0; i < 2; ++i) {
            int f = i * 256 + tid;
            int krow = f >> 5;
            int cq = f & 31;
            st4(&Bs[krow][cq * 4], ld4(W + (size_t)(kt + krow) * N + col0 + cq * 4));
        }
        __syncthreads();
#pragma unroll
        for (int kk = 0; kk < BK; ++kk) {
            float4 a0 = *reinterpret_cast<const float4*>(&As[kk][ty * 4]);
            float4 a1 = *reinterpret_cast<const float4*>(&As[kk][64 + ty * 4]);
            float4 b0 = *reinterpret_cast<const float4*>(&Bs[kk][tx * 4]);
            float4 b1 = *reinterpret_cast<const float4*>(&Bs[kk][64 + tx * 4]);
            float av[8] = {a0.x, a0.y, a0.z, a0.w, a1.x, a1.y, a1.z, a1.w};
            float bv[8] = {b0.x, b0.y, b0.z, b0.w, b1.x, b1.y, b1.z, b1.w};
#pragma unroll
            for (int i = 0; i < 8; ++i)
#pragma unroll
                for (int j = 0; j < 8; ++j)
                    acc[i][j] = fmaf(av[i], bv[j], acc[i][j]);
        }
        __syncthreads();
    }

    float4 bvlo = ld4(bias + col0 + tx * 4);
    float4 bvhi = ld4(bias + col0 + 64 + tx * 4);
    float bb[8] = {bvlo.x, bvlo.y, bvlo.z, bvlo.w, bvhi.x, bvhi.y, bvhi.z, bvhi.w};
    float sc[8], sh[8];
    if constexpr (OUTM == 2) {
        float4 s0 = ld4(scl + col0 + tx * 4);
        float4 s1 = ld4(scl + col0 + 64 + tx * 4);
        float4 h0 = ld4(shf + col0 + tx * 4);
        float4 h1 = ld4(shf + col0 + 64 + tx * 4);
        sc[0]=s0.x; sc[1]=s0.y; sc[2]=s0.z; sc[3]=s0.w;
        sc[4]=s1.x; sc[5]=s1.y; sc[6]=s1.z; sc[7]=s1.w;
        sh[0]=h0.x; sh[1]=h0.y; sh[2]=h0.z; sh[3]=h0.w;
        sh[4]=h1.x; sh[5]=h1.y; sh[6]=h1.z; sh[7]=h1.w;
    }
#pragma unroll
    for (int i = 0; i < 8; ++i) {
        int r = row0 + (i >> 2) * 64 + ty * 4 + (i & 3);
        if (r < M) {
            float v[8];
#pragma unroll
            for (int j = 0; j < 8; ++j) v[j] = acc[i][j] + bb[j];
            if constexpr (OUTM == 2) {
#pragma unroll
                for (int j = 0; j < 8; ++j) v[j] = fmaf(v[j], sc[j], sh[j]);
            }
#pragma unroll
            for (int j = 0; j < 8; ++j) v[j] = fmaxf(v[j], 0.f);
            st4(C + (size_t)r * N + col0 + tx * 4,      make_float4(v[0], v[1], v[2], v[3]));
            st4(C + (size_t)r * N + col0 + 64 + tx * 4, make_float4(v[4], v[5], v[6], v[7]));
        }
    }
}

// ---------------- Global add pool (batch is sorted) ------------------------
__device__ __forceinline__ int lower_bound_i(const int* a, int n, int key) {
    int lo = 0, hi = n;
    while (lo < hi) {
        int mid = (lo + hi) >> 1;
        if (a[mid] < key) lo = mid + 1; else hi = mid;
    }
    return lo;
}

__global__ __launch_bounds__(256) void pool_k(
    const float* __restrict__ H, const int* __restrict__ batch,
    float* __restrict__ out)
{
    int g = blockIdx.x;
    int col = threadIdx.x;
    int lo = lower_bound_i(batch, NN, g);
    int hi = lower_bound_i(batch, NN, g + 1);
    float acc = 0.f;
    for (int n = lo; n < hi; ++n) acc += H[(size_t)n * DD + col];
    out[(size_t)g * DD + col] = acc;
}

// ---------------------------------------------------------------------------
extern "C" void kernel_launch(void* const* d_in, const int* in_sizes, int n_in,
                              void* d_out, int out_size, void* d_ws, size_t ws_size,
                              hipStream_t stream)
{
    const int*   x        = (const int*)d_in[0];
    const int*   ei       = (const int*)d_in[1];
    const int*   ea       = (const int*)d_in[2];
    const int*   batch    = (const int*)d_in[3];
    const float* atom_emb = (const float*)d_in[4];
    const float* bond1    = (const float*)d_in[5];
    const float* bond2    = (const float*)d_in[6];
    const float* c1_w1    = (const float*)d_in[7];
    const float* c1_b1    = (const float*)d_in[8];
    const float* c1_g     = (const float*)d_in[9];
    const float* c1_be    = (const float*)d_in[10];
    const float* c1_w2    = (const float*)d_in[11];
    const float* c1_b2    = (const float*)d_in[12];
    const float* c2_w1    = (const float*)d_in[13];
    const float* c2_b1    = (const float*)d_in[14];
    const float* c2_g     = (const float*)d_in[15];
    const float* c2_be    = (const float*)d_in[16];
    const float* c2_w2    = (const float*)d_in[17];
    const float* c2_b2    = (const float*)d_in[18];
    float* out = (float*)d_out;

    // ---- workspace layout (~245 MB total) ----
    float* H      = (float*)d_ws;                      // [NN,256]  102.4 MB
    float* Z      = H + (size_t)NN * DD;               // [NN,256]  102.4 MB
    float* ystrip = Z + (size_t)NN * DD;               // [12800,512] 26.2 MB
    float* G      = ystrip + (size_t)STRIP * 512;      // [256,256]
    float* cs     = G + 65536;                         // [256]
    float* scl    = cs + 256;                          // [512]
    float* shf    = scl + 512;                         // [512]
    int* cnt    = (int*)(shf + 512);                   // [SCAN_N]
    int* rs     = cnt + SCAN_N;                        // [SCAN_N]
    int* bsum   = rs + SCAN_N;                         // [512]
    int* boff   = bsum + 512;                          // [512]
    int* cursor = boff + 512;                          // [NN]
    int* perm   = cursor + NN;                         // [NE]

    const int eb = (NE + 255) / 256;

    // zero accumulators (kernel, not memset: graph-capture safe)
    zero_k<<<(SCAN_N + 255) / 256, 256, 0, stream>>>((float*)cnt, SCAN_N);
    zero_k<<<(65792 + 255) / 256, 256, 0, stream>>>(G, 65792);   // G + cs

    // atom encode -> H
    atom_embed_k<<<NN / 4, 256, 0, stream>>>(x, atom_emb, H);

    // CSR build (dst-sorted edge permutation; reused by both convs)
    hist_k<<<eb, 256, 0, stream>>>(ei, cnt);
    scan1_k<<<SCAN_B, 256, 0, stream>>>(cnt, bsum);
    scan2_k<<<1, 512, 0, stream>>>(bsum, boff);
    scan3_k<<<SCAN_B, 256, 0, stream>>>(cnt, boff, rs, cursor);
    scatter_k<<<eb, 256, 0, stream>>>(ei, cursor, perm);

    // ================= conv1 =================
    gather_agg_k<<<NN / 4, 256, 0, stream>>>(H, ei, ea, bond1, rs, perm, Z);
    gram_k<<<4 * NGCH, 256, 0, stream>>>(Z, G);
    colsum_k<<<SCAN_B, 256, 0, stream>>>(Z, cs);
    bnprep_k<<<512, 256, 0, stream>>>(G, cs, c1_w1, c1_b1, c1_g, c1_be, scl, shf, 512);
    for (int s = 0; s < NSTRIP; ++s) {
        int r0 = s * STRIP;
        int Ms = (NN - r0 < STRIP) ? NN - r0 : STRIP;
        int mt = (Ms + BM - 1) / BM;
        gemm_k<2><<<mt * (512 / BN), 256, 0, stream>>>(
            Z + (size_t)r0 * DD, c1_w1, c1_b1, ystrip, Ms, 512, 256, scl, shf);
        gemm_k<1><<<mt * (256 / BN), 256, 0, stream>>>(
            ystrip, c1_w2, c1_b2, H + (size_t)r0 * DD, Ms, 256, 512, nullptr, nullptr);
    }

    // ================= conv2 =================
    zero_k<<<(65792 + 255) / 256, 256, 0, stream>>>(G, 65792);   // re-zero G + cs
    gather_agg_k<<<NN / 4, 256, 0, stream>>>(H, ei, ea, bond2, rs, perm, Z);
    gram_k<<<4 * NGCH, 256, 0, stream>>>(Z, G);
    colsum_k<<<SCAN_B, 256, 0, stream>>>(Z, cs);
    bnprep_k<<<256, 256, 0, stream>>>(G, cs, c2_w1, c2_b1, c2_g, c2_be, scl, shf, 256);
    for (int s = 0; s < NSTRIP; ++s) {
        int r0 = s * STRIP;
        int Ms = (NN - r0 < STRIP) ? NN - r0 : STRIP;
        int mt = (Ms + BM - 1) / BM;
        gemm_k<2><<<mt * (256 / BN), 256, 0, stream>>>(
            Z + (size_t)r0 * DD, c2_w1, c2_b1, ystrip, Ms, 256, 256, scl, shf);
        gemm_k<1><<<mt * (256 / BN), 256, 0, stream>>>(
            ystrip, c2_w2, c2_b2, H + (size_t)r0 * DD, Ms, 256, 256, nullptr, nullptr);
    }

    // ---- pool ----
    pool_k<<<NG, 256, 0, stream>>>(H, batch, out);
}

// Round 4
// 3476.775 us; speedup vs baseline: 1.2589x; 1.2589x over previous
//
#include <hip/hip_runtime.h>

#define NN 100000
#define NE 3200000
#define NG 2048
#define DD 256
#define EPSV 1e-5f
#define SCAN_N 100096           // 391 * 256 >= NN+1
#define SCAN_B 391
#define GCH 1568                // gram split-K chunk rows (98 * 16)
#define NGCH 64                 // 64 * 1568 >= NN

__device__ __forceinline__ float4 ld4(const float* p) {
    return *reinterpret_cast<const float4*>(p);
}
__device__ __forceinline__ void st4(float* p, float4 v) {
    *reinterpret_cast<float4*>(p) = v;
}

// ---------------- zero fill (graph-capture-safe) ---------------------------
__global__ __launch_bounds__(256) void zero_k(float* __restrict__ p, int n) {
    int i = blockIdx.x * 256 + threadIdx.x;
    if (i < n) p[i] = 0.f;
}

// ---------------- Atom encoder --------------------------------------------
__global__ __launch_bounds__(256) void atom_embed_k(
    const int* __restrict__ x, const float* __restrict__ emb,
    float* __restrict__ H)
{
    int lane = threadIdx.x & 63;
    int n = blockIdx.x * 4 + (threadIdx.x >> 6);
    if (n >= NN) return;
    int c4 = lane * 4;
    float4 acc = make_float4(0.f, 0.f, 0.f, 0.f);
#pragma unroll
    for (int c = 0; c < 9; ++c) {
        int idx = x[n * 9 + c];
        float4 v = ld4(emb + (size_t)(c * 100 + idx) * DD + c4);
        acc.x += v.x; acc.y += v.y; acc.z += v.z; acc.w += v.w;
    }
    st4(H + (size_t)n * DD + c4, acc);
}

// ---------------- bond combo table: bcomb[combo][:] = t0 + t1 + t2 ---------
__global__ __launch_bounds__(256) void bcomb_k(const float* __restrict__ bond,
                                               float* __restrict__ bcomb)
{
    int combo = blockIdx.x;          // 0..999
    int col = threadIdx.x;
    int b0 = combo % 10, b1 = (combo / 10) % 10, b2 = combo / 100;
    bcomb[(size_t)combo * DD + col] =
        bond[(size_t)b0 * DD + col] +
        bond[(size_t)(10 + b1) * DD + col] +
        bond[(size_t)(20 + b2) * DD + col];
}

// ---------------- CSR build ------------------------------------------------
__global__ __launch_bounds__(256) void hist_k(const int* __restrict__ ei,
                                              int* __restrict__ cnt)
{
    int e = blockIdx.x * 256 + threadIdx.x;
    if (e < NE) atomicAdd(&cnt[ei[NE + e]], 1);
}

__global__ __launch_bounds__(256) void scan1_k(int* __restrict__ cnt,
                                               int* __restrict__ bsum)
{
    __shared__ int s[2][256];
    int t = threadIdx.x;
    int i = blockIdx.x * 256 + t;
    int v = cnt[i];
    s[0][t] = v;
    __syncthreads();
    int p = 0;
    for (int off = 1; off < 256; off <<= 1) {
        int xv = s[p][t];
        if (t >= off) xv += s[p][t - off];
        s[p ^ 1][t] = xv;
        p ^= 1;
        __syncthreads();
    }
    int inc = s[p][t];
    cnt[i] = inc - v;
    if (t == 255) bsum[blockIdx.x] = inc;
}

__global__ __launch_bounds__(512) void scan2_k(const int* __restrict__ bsum,
                                               int* __restrict__ boff)
{
    __shared__ int s[2][512];
    int t = threadIdx.x;
    int v = (t < SCAN_B) ? bsum[t] : 0;
    s[0][t] = v;
    __syncthreads();
    int p = 0;
    for (int off = 1; off < 512; off <<= 1) {
        int xv = s[p][t];
        if (t >= off) xv += s[p][t - off];
        s[p ^ 1][t] = xv;
        p ^= 1;
        __syncthreads();
    }
    boff[t] = s[p][t] - v;
}

__global__ __launch_bounds__(256) void scan3_k(const int* __restrict__ cnt,
                                               const int* __restrict__ boff,
                                               int* __restrict__ rs,
                                               int* __restrict__ cursor)
{
    int i = blockIdx.x * 256 + threadIdx.x;
    int v = cnt[i] + boff[blockIdx.x];
    rs[i] = v;
    if (i < NN) cursor[i] = v;
}

// scatter: meta[pos] = (src<<10) | (b0 + 10*b1 + 100*b2)
__global__ __launch_bounds__(256) void scatter_k(const int* __restrict__ ei,
                                                 const int* __restrict__ ea,
                                                 int* __restrict__ cursor,
                                                 int* __restrict__ meta)
{
    int e = blockIdx.x * 256 + threadIdx.x;
    if (e >= NE) return;
    int src = ei[e];
    int dst = ei[NE + e];
    int combo = ea[e * 3 + 0] + 10 * ea[e * 3 + 1] + 100 * ea[e * 3 + 2];
    int pos = atomicAdd(&cursor[dst], 1);
    meta[pos] = (src << 10) | combo;
}

// ---------------- Gather-aggregate: Z[n] = H[n] + sum relu(H[src]+bcomb) ---
__global__ __launch_bounds__(256) void gather_agg_k(
    const float* __restrict__ H, const float* __restrict__ bcomb,
    const int* __restrict__ rs, const int* __restrict__ meta,
    float* __restrict__ Z)
{
    int lane = threadIdx.x & 63;
    int n = blockIdx.x * 4 + (threadIdx.x >> 6);
    if (n >= NN) return;
    int c4 = lane * 4;
    float4 acc = ld4(H + (size_t)n * DD + c4);       // the "+ h" term
    int lo = rs[n], hi = rs[n + 1];
    int t = lo;
    for (; t + 2 <= hi; t += 2) {
        int m0 = meta[t];
        int m1 = meta[t + 1];
        const float* h0 = H + (size_t)(m0 >> 10) * DD + c4;
        const float* g0 = bcomb + (size_t)(m0 & 1023) * DD + c4;
        const float* h1 = H + (size_t)(m1 >> 10) * DD + c4;
        const float* g1 = bcomb + (size_t)(m1 & 1023) * DD + c4;
        float4 v0 = ld4(h0);
        float4 b0 = ld4(g0);
        float4 v1 = ld4(h1);
        float4 b1 = ld4(g1);
        acc.x += fmaxf(v0.x + b0.x, 0.f) + fmaxf(v1.x + b1.x, 0.f);
        acc.y += fmaxf(v0.y + b0.y, 0.f) + fmaxf(v1.y + b1.y, 0.f);
        acc.z += fmaxf(v0.z + b0.z, 0.f) + fmaxf(v1.z + b1.z, 0.f);
        acc.w += fmaxf(v0.w + b0.w, 0.f) + fmaxf(v1.w + b1.w, 0.f);
    }
    if (t < hi) {
        int m0 = meta[t];
        float4 v0 = ld4(H + (size_t)(m0 >> 10) * DD + c4);
        float4 b0 = ld4(bcomb + (size_t)(m0 & 1023) * DD + c4);
        acc.x += fmaxf(v0.x + b0.x, 0.f);
        acc.y += fmaxf(v0.y + b0.y, 0.f);
        acc.z += fmaxf(v0.z + b0.z, 0.f);
        acc.w += fmaxf(v0.w + b0.w, 0.f);
    }
    st4(Z + (size_t)n * DD + c4, acc);
}

// ---------------- Gram: G += Z^T Z (split-K, atomics) ----------------------
__global__ __launch_bounds__(256) void gram_k(const float* __restrict__ Z,
                                              float* __restrict__ G)
{
    __shared__ __align__(16) float As[16][132];
    __shared__ __align__(16) float Bs[16][132];
    const int tid = threadIdx.x;
    const int bj = blockIdx.x & 1;
    const int bi = (blockIdx.x >> 1) & 1;
    const int ch = blockIdx.x >> 2;
    const int rbase = ch * GCH;
    const int tx = tid & 15;
    const int ty = tid >> 4;

    float acc[8][8] = {};

    for (int kt = 0; kt < GCH; kt += 16) {
#pragma unroll
        for (int i = 0; i < 2; ++i) {
            int f = i * 256 + tid;
            int kk = f >> 5;
            int cq = f & 31;
            int r = rbase + kt + kk;
            float4 a = make_float4(0.f, 0.f, 0.f, 0.f);
            float4 b = make_float4(0.f, 0.f, 0.f, 0.f);
            if (r < NN) {
                a = ld4(Z + (size_t)r * DD + bi * 128 + cq * 4);
                b = ld4(Z + (size_t)r * DD + bj * 128 + cq * 4);
            }
            st4(&As[kk][cq * 4], a);
            st4(&Bs[kk][cq * 4], b);
        }
        __syncthreads();
#pragma unroll
        for (int kk = 0; kk < 16; ++kk) {
            float4 a0 = *reinterpret_cast<const float4*>(&As[kk][ty * 4]);
            float4 a1 = *reinterpret_cast<const float4*>(&As[kk][64 + ty * 4]);
            float4 b0 = *reinterpret_cast<const float4*>(&Bs[kk][tx * 4]);
            float4 b1 = *reinterpret_cast<const float4*>(&Bs[kk][64 + tx * 4]);
            float av[8] = {a0.x, a0.y, a0.z, a0.w, a1.x, a1.y, a1.z, a1.w};
            float bv[8] = {b0.x, b0.y, b0.z, b0.w, b1.x, b1.y, b1.z, b1.w};
#pragma unroll
            for (int i = 0; i < 8; ++i)
#pragma unroll
                for (int j = 0; j < 8; ++j)
                    acc[i][j] = fmaf(av[i], bv[j], acc[i][j]);
        }
        __syncthreads();
    }
#pragma unroll
    for (int i = 0; i < 8; ++i) {
        int row = bi * 128 + (i >> 2) * 64 + ty * 4 + (i & 3);
#pragma unroll
        for (int j = 0; j < 8; ++j) {
            int col = bj * 128 + (j >> 2) * 64 + tx * 4 + (j & 3);
            atomicAdd(&G[row * 256 + col], acc[i][j]);
        }
    }
}

// ---------------- column sums of Z ----------------------------------------
__global__ __launch_bounds__(256) void colsum_k(const float* __restrict__ Z,
                                                float* __restrict__ cs)
{
    int t = threadIdx.x;
    int r0 = blockIdx.x * 256;
    int r1 = r0 + 256 < NN ? r0 + 256 : NN;
    float acc = 0.f;
    for (int r = r0; r < r1; ++r) acc += Z[(size_t)r * DD + t];
    atomicAdd(&cs[t], acc);
}

// ---------------- BN prep from Gram (f64 finalize) -------------------------
__global__ __launch_bounds__(256) void bnprep_k(
    const float* __restrict__ G, const float* __restrict__ cs,
    const float* __restrict__ W, const float* __restrict__ b,
    const float* __restrict__ g, const float* __restrict__ be,
    float* __restrict__ scl, float* __restrict__ shf, int N)
{
    __shared__ float wv[256];
    __shared__ double r1[256];
    __shared__ double r2[256];
    int c = blockIdx.x;
    int t = threadIdx.x;
    wv[t] = W[t * N + c];
    __syncthreads();
    double gd = 0.0;
    const float* Gr = G + t * 256;
    for (int j = 0; j < 256; ++j) gd += (double)Gr[j] * (double)wv[j];
    r1[t] = (double)wv[t] * gd;
    r2[t] = (double)cs[t] * (double)wv[t];
    __syncthreads();
    for (int off = 128; off > 0; off >>= 1) {
        if (t < off) { r1[t] += r1[t + off]; r2[t] += r2[t + off]; }
        __syncthreads();
    }
    if (t == 0) {
        double szw = r2[0];            // sum over rows of (zW)_c
        double s2zw = r1[0];           // sum over rows of (zW)_c^2
        double bb = (double)b[c];
        double fN = (double)NN;
        double S1 = szw + fN * bb;
        double S2 = s2zw + 2.0 * bb * szw + fN * bb * bb;
        double mu = S1 / fN;
        double var = S2 / fN - mu * mu;
        float s = g[c] * rsqrtf((float)var + EPSV);
        scl[c] = s;
        shf[c] = be[c] - (float)mu * s;
    }
}

// ---------------- Tiled f32 GEMM: C = A @ W + bias, fused epilogue ---------
// OUTM=1: relu(y);  OUTM=2: relu(y*scl + shf)  (BN folded)
#define BM 128
#define BN 128
#define BK 16

template <int OUTM>
__global__ __launch_bounds__(256) void gemm_k(
    const float* __restrict__ A, const float* __restrict__ W,
    const float* __restrict__ bias, float* __restrict__ C,
    int M, int N, int K,
    const float* __restrict__ scl, const float* __restrict__ shf)
{
    __shared__ __align__(16) float As[BK][BM + 4];
    __shared__ __align__(16) float Bs[BK][BN + 4];

    const int tid = threadIdx.x;
    const int ntx = N / BN;
    const int bx = blockIdx.x % ntx;
    const int by = blockIdx.x / ntx;
    const int tx = tid & 15;
    const int ty = tid >> 4;
    const int row0 = by * BM;
    const int col0 = bx * BN;

    float acc[8][8] = {};

    for (int kt = 0; kt < K; kt += BK) {
#pragma unroll
        for (int i = 0; i < 2; ++i) {
            int f = i * 256 + tid;
            int row = f >> 2;
            int q = f & 3;
            int r = row0 + row;
            if (r >= M) r = M - 1;
            float4 a = ld4(A + (size_t)r * K + kt + q * 4);
            As[q * 4 + 0][row] = a.x;
            As[q * 4 + 1][row] = a.y;
            As[q * 4 + 2][row] = a.z;
            As[q * 4 + 3][row] = a.w;
        }
#pragma unroll
        for (int i = 0; i < 2; ++i) {
            int f = i * 256 + tid;
            int krow = f >> 5;
            int cq = f & 31;
            st4(&Bs[krow][cq * 4], ld4(W + (size_t)(kt + krow) * N + col0 + cq * 4));
        }
        __syncthreads();
#pragma unroll
        for (int kk = 0; kk < BK; ++kk) {
            float4 a0 = *reinterpret_cast<const float4*>(&As[kk][ty * 4]);
            float4 a1 = *reinterpret_cast<const float4*>(&As[kk][64 + ty * 4]);
            float4 b0 = *reinterpret_cast<const float4*>(&Bs[kk][tx * 4]);
            float4 b1 = *reinterpret_cast<const float4*>(&Bs[kk][64 + tx * 4]);
            float av[8] = {a0.x, a0.y, a0.z, a0.w, a1.x, a1.y, a1.z, a1.w};
            float bv[8] = {b0.x, b0.y, b0.z, b0.w, b1.x, b1.y, b1.z, b1.w};
#pragma unroll
            for (int i = 0; i < 8; ++i)
#pragma unroll
                for (int j = 0; j < 8; ++j)
                    acc[i][j] = fmaf(av[i], bv[j], acc[i][j]);
        }
        __syncthreads();
    }

    float4 bvlo = ld4(bias + col0 + tx * 4);
    float4 bvhi = ld4(bias + col0 + 64 + tx * 4);
    float bb[8] = {bvlo.x, bvlo.y, bvlo.z, bvlo.w, bvhi.x, bvhi.y, bvhi.z, bvhi.w};
    float sc[8], sh[8];
    if constexpr (OUTM == 2) {
        float4 s0 = ld4(scl + col0 + tx * 4);
        float4 s1 = ld4(scl + col0 + 64 + tx * 4);
        float4 h0 = ld4(shf + col0 + tx * 4);
        float4 h1 = ld4(shf + col0 + 64 + tx * 4);
        sc[0]=s0.x; sc[1]=s0.y; sc[2]=s0.z; sc[3]=s0.w;
        sc[4]=s1.x; sc[5]=s1.y; sc[6]=s1.z; sc[7]=s1.w;
        sh[0]=h0.x; sh[1]=h0.y; sh[2]=h0.z; sh[3]=h0.w;
        sh[4]=h1.x; sh[5]=h1.y; sh[6]=h1.z; sh[7]=h1.w;
    }
#pragma unroll
    for (int i = 0; i < 8; ++i) {
        int r = row0 + (i >> 2) * 64 + ty * 4 + (i & 3);
        if (r < M) {
            float v[8];
#pragma unroll
            for (int j = 0; j < 8; ++j) v[j] = acc[i][j] + bb[j];
            if constexpr (OUTM == 2) {
#pragma unroll
                for (int j = 0; j < 8; ++j) v[j] = fmaf(v[j], sc[j], sh[j]);
            }
#pragma unroll
            for (int j = 0; j < 8; ++j) v[j] = fmaxf(v[j], 0.f);
            st4(C + (size_t)r * N + col0 + tx * 4,      make_float4(v[0], v[1], v[2], v[3]));
            st4(C + (size_t)r * N + col0 + 64 + tx * 4, make_float4(v[4], v[5], v[6], v[7]));
        }
    }
}

// ---------------- Global add pool (batch is sorted) ------------------------
__device__ __forceinline__ int lower_bound_i(const int* a, int n, int key) {
    int lo = 0, hi = n;
    while (lo < hi) {
        int mid = (lo + hi) >> 1;
        if (a[mid] < key) lo = mid + 1; else hi = mid;
    }
    return lo;
}

__global__ __launch_bounds__(256) void pool_k(
    const float* __restrict__ H, const int* __restrict__ batch,
    float* __restrict__ out)
{
    int g = blockIdx.x;
    int col = threadIdx.x;
    int lo = lower_bound_i(batch, NN, g);
    int hi = lower_bound_i(batch, NN, g + 1);
    float acc = 0.f;
    for (int n = lo; n < hi; ++n) acc += H[(size_t)n * DD + col];
    out[(size_t)g * DD + col] = acc;
}

// ---------------------------------------------------------------------------
extern "C" void kernel_launch(void* const* d_in, const int* in_sizes, int n_in,
                              void* d_out, int out_size, void* d_ws, size_t ws_size,
                              hipStream_t stream)
{
    const int*   x        = (const int*)d_in[0];
    const int*   ei       = (const int*)d_in[1];
    const int*   ea       = (const int*)d_in[2];
    const int*   batch    = (const int*)d_in[3];
    const float* atom_emb = (const float*)d_in[4];
    const float* bond1    = (const float*)d_in[5];
    const float* bond2    = (const float*)d_in[6];
    const float* c1_w1    = (const float*)d_in[7];
    const float* c1_b1    = (const float*)d_in[8];
    const float* c1_g     = (const float*)d_in[9];
    const float* c1_be    = (const float*)d_in[10];
    const float* c1_w2    = (const float*)d_in[11];
    const float* c1_b2    = (const float*)d_in[12];
    const float* c2_w1    = (const float*)d_in[13];
    const float* c2_b1    = (const float*)d_in[14];
    const float* c2_g     = (const float*)d_in[15];
    const float* c2_be    = (const float*)d_in[16];
    const float* c2_w2    = (const float*)d_in[17];
    const float* c2_b2    = (const float*)d_in[18];
    float* out = (float*)d_out;

    // ---- fixed workspace layout (~220 MB) ----
    float* H      = (float*)d_ws;                      // [NN,256]
    float* Z      = H + (size_t)NN * DD;               // [NN,256]
    float* G      = Z + (size_t)NN * DD;               // [256,256]
    float* cs     = G + 65536;                         // [256]
    float* scl    = cs + 256;                          // [512]
    float* shf    = scl + 512;                         // [512]
    float* bcomb  = shf + 512;                         // [1000,256]
    int* cnt    = (int*)(bcomb + 1000 * DD);           // [SCAN_N]
    int* rs     = cnt + SCAN_N;                        // [SCAN_N]
    int* bsum   = rs + SCAN_N;                         // [512]
    int* boff   = bsum + 512;                          // [512]
    int* cursor = boff + 512;                          // [NN]
    int* meta   = cursor + NN;                         // [NE]
    float* ystrip = (float*)(meta + NE);               // [strip,512] dynamic

    // dynamic strip size from remaining workspace
    size_t fixed_bytes = (size_t)((char*)ystrip - (char*)d_ws);
    size_t avail = ws_size > fixed_bytes ? ws_size - fixed_bytes : 0;
    int strip = (int)(avail / (512 * sizeof(float)));
    strip = (strip / 128) * 128;
    if (strip > 25600) strip = 25600;
    if (strip < 128) strip = 128;

    const int eb = (NE + 255) / 256;

    // zero accumulators (kernels, not memset: graph-capture safe)
    zero_k<<<(SCAN_N + 255) / 256, 256, 0, stream>>>((float*)cnt, SCAN_N);
    zero_k<<<(65792 + 255) / 256, 256, 0, stream>>>(G, 65792);   // G + cs

    // atom encode -> H
    atom_embed_k<<<NN / 4, 256, 0, stream>>>(x, atom_emb, H);

    // CSR build with fused edge-meta (dst-sorted; conv-invariant)
    hist_k<<<eb, 256, 0, stream>>>(ei, cnt);
    scan1_k<<<SCAN_B, 256, 0, stream>>>(cnt, bsum);
    scan2_k<<<1, 512, 0, stream>>>(bsum, boff);
    scan3_k<<<SCAN_B, 256, 0, stream>>>(cnt, boff, rs, cursor);
    scatter_k<<<eb, 256, 0, stream>>>(ei, ea, cursor, meta);

    // ================= conv1 =================
    bcomb_k<<<1000, 256, 0, stream>>>(bond1, bcomb);
    gather_agg_k<<<NN / 4, 256, 0, stream>>>(H, bcomb, rs, meta, Z);
    gram_k<<<4 * NGCH, 256, 0, stream>>>(Z, G);
    colsum_k<<<SCAN_B, 256, 0, stream>>>(Z, cs);
    bnprep_k<<<512, 256, 0, stream>>>(G, cs, c1_w1, c1_b1, c1_g, c1_be, scl, shf, 512);
    for (int r0 = 0; r0 < NN; r0 += strip) {
        int Ms = (NN - r0 < strip) ? NN - r0 : strip;
        int mt = (Ms + BM - 1) / BM;
        gemm_k<2><<<mt * (512 / BN), 256, 0, stream>>>(
            Z + (size_t)r0 * DD, c1_w1, c1_b1, ystrip, Ms, 512, 256, scl, shf);
        gemm_k<1><<<mt * (256 / BN), 256, 0, stream>>>(
            ystrip, c1_w2, c1_b2, H + (size_t)r0 * DD, Ms, 256, 512, nullptr, nullptr);
    }

    // ================= conv2 =================
    zero_k<<<(65792 + 255) / 256, 256, 0, stream>>>(G, 65792);   // re-zero G + cs
    bcomb_k<<<1000, 256, 0, stream>>>(bond2, bcomb);
    gather_agg_k<<<NN / 4, 256, 0, stream>>>(H, bcomb, rs, meta, Z);
    gram_k<<<4 * NGCH, 256, 0, stream>>>(Z, G);
    colsum_k<<<SCAN_B, 256, 0, stream>>>(Z, cs);
    bnprep_k<<<256, 256, 0, stream>>>(G, cs, c2_w1, c2_b1, c2_g, c2_be, scl, shf, 256);
    for (int r0 = 0; r0 < NN; r0 += strip) {
        int Ms = (NN - r0 < strip) ? NN - r0 : strip;
        int mt = (Ms + BM - 1) / BM;
        gemm_k<2><<<mt * (256 / BN), 256, 0, stream>>>(
            Z + (size_t)r0 * DD, c2_w1, c2_b1, ystrip, Ms, 256, 256, scl, shf);
        gemm_k<1><<<mt * (256 / BN), 256, 0, stream>>>(
            ystrip, c2_w2, c2_b2, H + (size_t)r0 * DD, Ms, 256, 256, nullptr, nullptr);
    }

    // ---- pool ----
    pool_k<<<NG, 256, 0, stream>>>(H, batch, out);
}

// Round 5
// 3025.324 us; speedup vs baseline: 1.4467x; 1.1492x over previous
//
#include <hip/hip_runtime.h>

#define NN 100000
#define NE 3200000
#define NG 2048
#define DD 256
#define EPSV 1e-5f
#define SCAN_N 100096           // 391 * 256 >= NN+1
#define SCAN_B 391
#define GCH 1568                // gram split-K chunk rows
#define NGCH 64

typedef unsigned int uint32;
typedef __attribute__((ext_vector_type(4))) unsigned int uivec4;
typedef __attribute__((ext_vector_type(4))) float f32x4;
typedef __attribute__((ext_vector_type(8))) short short8_t;

__device__ __forceinline__ float4 ld4(const float* p) {
    return *reinterpret_cast<const float4*>(p);
}
__device__ __forceinline__ void st4(float* p, float4 v) {
    *reinterpret_cast<float4*>(p) = v;
}
__device__ __forceinline__ uivec4 ldu4(const uint32* p) {
    return *reinterpret_cast<const uivec4*>(p);
}

// ---- packed split-bf16: u = hi | (lo<<16); x ~= f32(hi<<16) + f32(lo<<16) --
__device__ __forceinline__ uint32 packsplit(float x) {
    uint32 u = __float_as_uint(x);
    uint32 hb = u >> 16;
    float hf = __uint_as_float(hb << 16);
    float lo = x - hf;
    uint32 lb = __float_as_uint(lo) >> 16;
    return hb | (lb << 16);
}
__device__ __forceinline__ float unpacksplit(uint32 u) {
    return __uint_as_float(u << 16) + __uint_as_float(u & 0xffff0000u);
}

// ---------------- zero fill ------------------------------------------------
__global__ __launch_bounds__(256) void zero_k(float* __restrict__ p, int n) {
    int i = blockIdx.x * 256 + threadIdx.x;
    if (i < n) p[i] = 0.f;
}

// ---------------- pack a f32 matrix into split form ------------------------
__global__ __launch_bounds__(256) void packmat_k(const float* __restrict__ X,
                                                 uint32* __restrict__ Xp, int n) {
    int i = blockIdx.x * 256 + threadIdx.x;
    if (i < n) Xp[i] = packsplit(X[i]);
}

// ---------------- Atom encoder (writes packed H) ---------------------------
__global__ __launch_bounds__(256) void atom_embed_k(
    const int* __restrict__ x, const float* __restrict__ emb,
    uint32* __restrict__ Hp)
{
    int lane = threadIdx.x & 63;
    int n = blockIdx.x * 4 + (threadIdx.x >> 6);
    if (n >= NN) return;
    int c4 = lane * 4;
    float4 acc = make_float4(0.f, 0.f, 0.f, 0.f);
#pragma unroll
    for (int c = 0; c < 9; ++c) {
        int idx = x[n * 9 + c];
        float4 v = ld4(emb + (size_t)(c * 100 + idx) * DD + c4);
        acc.x += v.x; acc.y += v.y; acc.z += v.z; acc.w += v.w;
    }
    uivec4 o;
    o[0] = packsplit(acc.x); o[1] = packsplit(acc.y);
    o[2] = packsplit(acc.z); o[3] = packsplit(acc.w);
    *reinterpret_cast<uivec4*>(Hp + (size_t)n * DD + c4) = o;
}

// ---------------- bond combo table (f32) -----------------------------------
__global__ __launch_bounds__(256) void bcomb_k(const float* __restrict__ bond,
                                               float* __restrict__ bcomb)
{
    int combo = blockIdx.x;          // 0..999
    int col = threadIdx.x;
    int b0 = combo % 10, b1 = (combo / 10) % 10, b2 = combo / 100;
    bcomb[(size_t)combo * DD + col] =
        bond[(size_t)b0 * DD + col] +
        bond[(size_t)(10 + b1) * DD + col] +
        bond[(size_t)(20 + b2) * DD + col];
}

// ---------------- CSR build ------------------------------------------------
__global__ __launch_bounds__(256) void hist_k(const int* __restrict__ ei,
                                              int* __restrict__ cnt)
{
    int e = blockIdx.x * 256 + threadIdx.x;
    if (e < NE) atomicAdd(&cnt[ei[NE + e]], 1);
}

__global__ __launch_bounds__(256) void scan1_k(int* __restrict__ cnt,
                                               int* __restrict__ bsum)
{
    __shared__ int s[2][256];
    int t = threadIdx.x;
    int i = blockIdx.x * 256 + t;
    int v = cnt[i];
    s[0][t] = v;
    __syncthreads();
    int p = 0;
    for (int off = 1; off < 256; off <<= 1) {
        int xv = s[p][t];
        if (t >= off) xv += s[p][t - off];
        s[p ^ 1][t] = xv;
        p ^= 1;
        __syncthreads();
    }
    int inc = s[p][t];
    cnt[i] = inc - v;
    if (t == 255) bsum[blockIdx.x] = inc;
}

__global__ __launch_bounds__(512) void scan2_k(const int* __restrict__ bsum,
                                               int* __restrict__ boff)
{
    __shared__ int s[2][512];
    int t = threadIdx.x;
    int v = (t < SCAN_B) ? bsum[t] : 0;
    s[0][t] = v;
    __syncthreads();
    int p = 0;
    for (int off = 1; off < 512; off <<= 1) {
        int xv = s[p][t];
        if (t >= off) xv += s[p][t - off];
        s[p ^ 1][t] = xv;
        p ^= 1;
        __syncthreads();
    }
    boff[t] = s[p][t] - v;
}

__global__ __launch_bounds__(256) void scan3_k(const int* __restrict__ cnt,
                                               const int* __restrict__ boff,
                                               int* __restrict__ rs,
                                               int* __restrict__ cursor)
{
    int i = blockIdx.x * 256 + threadIdx.x;
    int v = cnt[i] + boff[blockIdx.x];
    rs[i] = v;
    if (i < NN) cursor[i] = v;
}

__global__ __launch_bounds__(256) void scatter_k(const int* __restrict__ ei,
                                                 const int* __restrict__ ea,
                                                 int* __restrict__ cursor,
                                                 int* __restrict__ meta)
{
    int e = blockIdx.x * 256 + threadIdx.x;
    if (e >= NE) return;
    int src = ei[e];
    int dst = ei[NE + e];
    int combo = ea[e * 3 + 0] + 10 * ea[e * 3 + 1] + 100 * ea[e * 3 + 2];
    int pos = atomicAdd(&cursor[dst], 1);
    meta[pos] = (src << 10) | combo;
}

// ---------------- Gather-aggregate (packed in/out, x4 unroll) --------------
__device__ __forceinline__ void edge_acc(const uint32* __restrict__ Hp,
                                         const float* __restrict__ bcomb,
                                         int m, int c4,
                                         float& ax, float& ay, float& az, float& aw)
{
    uivec4 v = ldu4(Hp + (size_t)(m >> 10) * DD + c4);
    float4 b = ld4(bcomb + (size_t)(m & 1023) * DD + c4);
    ax += fmaxf(unpacksplit(v[0]) + b.x, 0.f);
    ay += fmaxf(unpacksplit(v[1]) + b.y, 0.f);
    az += fmaxf(unpacksplit(v[2]) + b.z, 0.f);
    aw += fmaxf(unpacksplit(v[3]) + b.w, 0.f);
}

__global__ __launch_bounds__(256) void gather_agg_k(
    const uint32* __restrict__ Hp, const float* __restrict__ bcomb,
    const int* __restrict__ rs, const int* __restrict__ meta,
    uint32* __restrict__ Zp)
{
    int lane = threadIdx.x & 63;
    int n = blockIdx.x * 4 + (threadIdx.x >> 6);
    if (n >= NN) return;
    int c4 = lane * 4;
    uivec4 hu = ldu4(Hp + (size_t)n * DD + c4);
    float ax = unpacksplit(hu[0]), ay = unpacksplit(hu[1]);
    float az = unpacksplit(hu[2]), aw = unpacksplit(hu[3]);
    int lo = rs[n], hi = rs[n + 1];
    int t = lo;
    for (; t + 4 <= hi; t += 4) {
        int m0 = meta[t], m1 = meta[t + 1], m2 = meta[t + 2], m3 = meta[t + 3];
        edge_acc(Hp, bcomb, m0, c4, ax, ay, az, aw);
        edge_acc(Hp, bcomb, m1, c4, ax, ay, az, aw);
        edge_acc(Hp, bcomb, m2, c4, ax, ay, az, aw);
        edge_acc(Hp, bcomb, m3, c4, ax, ay, az, aw);
    }
    for (; t < hi; ++t)
        edge_acc(Hp, bcomb, meta[t], c4, ax, ay, az, aw);
    uivec4 z;
    z[0] = packsplit(ax); z[1] = packsplit(ay);
    z[2] = packsplit(az); z[3] = packsplit(aw);
    __builtin_nontemporal_store(z, reinterpret_cast<uivec4*>(Zp + (size_t)n * DD + c4));
}

// ---------------- Gram: G += Z^T Z (unpack staging, f32 math) --------------
__global__ __launch_bounds__(256) void gram_k(const uint32* __restrict__ Zp,
                                              float* __restrict__ G)
{
    __shared__ __align__(16) float As[16][132];
    __shared__ __align__(16) float Bs[16][132];
    const int tid = threadIdx.x;
    const int bj = blockIdx.x & 1;
    const int bi = (blockIdx.x >> 1) & 1;
    const int ch = blockIdx.x >> 2;
    const int rbase = ch * GCH;
    const int tx = tid & 15;
    const int ty = tid >> 4;

    float acc[8][8] = {};

    for (int kt = 0; kt < GCH; kt += 16) {
#pragma unroll
        for (int i = 0; i < 2; ++i) {
            int f = i * 256 + tid;
            int kk = f >> 5;
            int cq = f & 31;
            int r = rbase + kt + kk;
            float4 a = make_float4(0.f, 0.f, 0.f, 0.f);
            float4 b = make_float4(0.f, 0.f, 0.f, 0.f);
            if (r < NN) {
                uivec4 ua = ldu4(Zp + (size_t)r * DD + bi * 128 + cq * 4);
                uivec4 ub = ldu4(Zp + (size_t)r * DD + bj * 128 + cq * 4);
                a = make_float4(unpacksplit(ua[0]), unpacksplit(ua[1]),
                                unpacksplit(ua[2]), unpacksplit(ua[3]));
                b = make_float4(unpacksplit(ub[0]), unpacksplit(ub[1]),
                                unpacksplit(ub[2]), unpacksplit(ub[3]));
            }
            st4(&As[kk][cq * 4], a);
            st4(&Bs[kk][cq * 4], b);
        }
        __syncthreads();
#pragma unroll
        for (int kk = 0; kk < 16; ++kk) {
            float4 a0 = *reinterpret_cast<const float4*>(&As[kk][ty * 4]);
            float4 a1 = *reinterpret_cast<const float4*>(&As[kk][64 + ty * 4]);
            float4 b0 = *reinterpret_cast<const float4*>(&Bs[kk][tx * 4]);
            float4 b1 = *reinterpret_cast<const float4*>(&Bs[kk][64 + tx * 4]);
            float av[8] = {a0.x, a0.y, a0.z, a0.w, a1.x, a1.y, a1.z, a1.w};
            float bv[8] = {b0.x, b0.y, b0.z, b0.w, b1.x, b1.y, b1.z, b1.w};
#pragma unroll
            for (int i = 0; i < 8; ++i)
#pragma unroll
                for (int j = 0; j < 8; ++j)
                    acc[i][j] = fmaf(av[i], bv[j], acc[i][j]);
        }
        __syncthreads();
    }
#pragma unroll
    for (int i = 0; i < 8; ++i) {
        int row = bi * 128 + (i >> 2) * 64 + ty * 4 + (i & 3);
#pragma unroll
        for (int j = 0; j < 8; ++j) {
            int col = bj * 128 + (j >> 2) * 64 + tx * 4 + (j & 3);
            atomicAdd(&G[row * 256 + col], acc[i][j]);
        }
    }
}

// ---------------- column sums ---------------------------------------------
__global__ __launch_bounds__(256) void colsum_k(const uint32* __restrict__ Zp,
                                                float* __restrict__ cs)
{
    int t = threadIdx.x;
    int r0 = blockIdx.x * 256;
    int r1 = r0 + 256 < NN ? r0 + 256 : NN;
    float acc = 0.f;
    for (int r = r0; r < r1; ++r) acc += unpacksplit(Zp[(size_t)r * DD + t]);
    atomicAdd(&cs[t], acc);
}

// ---------------- BN prep from Gram (f64 finalize) -------------------------
__global__ __launch_bounds__(256) void bnprep_k(
    const float* __restrict__ G, const float* __restrict__ cs,
    const float* __restrict__ W, const float* __restrict__ b,
    const float* __restrict__ g, const float* __restrict__ be,
    float* __restrict__ scl, float* __restrict__ shf, int N)
{
    __shared__ float wv[256];
    __shared__ double r1[256];
    __shared__ double r2[256];
    int c = blockIdx.x;
    int t = threadIdx.x;
    wv[t] = W[t * N + c];
    __syncthreads();
    double gd = 0.0;
    const float* Gr = G + t * 256;
    for (int j = 0; j < 256; ++j) gd += (double)Gr[j] * (double)wv[j];
    r1[t] = (double)wv[t] * gd;
    r2[t] = (double)cs[t] * (double)wv[t];
    __syncthreads();
    for (int off = 128; off > 0; off >>= 1) {
        if (t < off) { r1[t] += r1[t + off]; r2[t] += r2[t + off]; }
        __syncthreads();
    }
    if (t == 0) {
        double szw = r2[0];
        double s2zw = r1[0];
        double bb = (double)b[c];
        double fN = (double)NN;
        double S1 = szw + fN * bb;
        double S2 = s2zw + 2.0 * bb * szw + fN * bb * bb;
        double mu = S1 / fN;
        double var = S2 / fN - mu * mu;
        float s = g[c] * rsqrtf((float)var + EPSV);
        scl[c] = s;
        shf[c] = be[c] - (float)mu * s;
    }
}

// ---------------- split-bf16 MFMA GEMM -------------------------------------
// C = relu([BN](A @ W + bias)); A, W, C all packed-split uint32.
// 128x128 tile, 4 waves (2x2 of 64x64), BK=32, 3 MFMA products (hh, hl, lh).
// A staged in LDS (pitch 36 uint); W fragments loaded直接 from global (L2-hot).
template <int OUTM>
__global__ __launch_bounds__(256) void gemm_mfma_k(
    const uint32* __restrict__ Ap, const uint32* __restrict__ Wp,
    const float* __restrict__ bias, uint32* __restrict__ Cp,
    int M, int N, int K,
    const float* __restrict__ scl, const float* __restrict__ shf)
{
    __shared__ uint32 As[128][36];

    const int tid = threadIdx.x;
    const int lane = tid & 63;
    const int l15 = lane & 15;
    const int l4 = lane >> 4;
    const int wave = tid >> 6;
    const int wm = wave >> 1, wn = wave & 1;
    const int ntx = N / 128;
    const int bx = blockIdx.x % ntx;
    const int by = blockIdx.x / ntx;
    const int row0 = by * 128, col0 = bx * 128;

    f32x4 acc[4][4] = {};

    for (int kt = 0; kt < K; kt += 32) {
        __syncthreads();
        // stage A tile: 128 rows x 32 uint, coalesced
#pragma unroll
        for (int i = 0; i < 4; ++i) {
            int f = i * 256 + tid;
            int row = f >> 3, q = f & 7;
            int r = row0 + row;
            if (r >= M) r = M - 1;
            *reinterpret_cast<uivec4*>(&As[row][q * 4]) =
                ldu4(Ap + (size_t)r * K + kt + q * 4);
        }
        __syncthreads();

        // A fragments from LDS
        short8_t ah[4], al[4];
#pragma unroll
        for (int mi = 0; mi < 4; ++mi) {
            int m = wm * 64 + mi * 16 + l15;
            uivec4 u0 = *reinterpret_cast<const uivec4*>(&As[m][l4 * 8]);
            uivec4 u1 = *reinterpret_cast<const uivec4*>(&As[m][l4 * 8 + 4]);
            short8_t h, l;
#pragma unroll
            for (int j = 0; j < 4; ++j) {
                h[j] = (short)(u0[j] & 0xffff);
                l[j] = (short)(u0[j] >> 16);
                h[4 + j] = (short)(u1[j] & 0xffff);
                l[4 + j] = (short)(u1[j] >> 16);
            }
            ah[mi] = h; al[mi] = l;
        }
        // B fragments direct from packed W (lanes cover consecutive cols)
        short8_t bh[4], bl[4];
#pragma unroll
        for (int ni = 0; ni < 4; ++ni) {
            int col = col0 + wn * 64 + ni * 16 + l15;
            const uint32* wp = Wp + (size_t)(kt + l4 * 8) * N + col;
            short8_t h, l;
#pragma unroll
            for (int j = 0; j < 8; ++j) {
                uint32 u = wp[(size_t)j * N];
                h[j] = (short)(u & 0xffff);
                l[j] = (short)(u >> 16);
            }
            bh[ni] = h; bl[ni] = l;
        }
#pragma unroll
        for (int mi = 0; mi < 4; ++mi)
#pragma unroll
            for (int ni = 0; ni < 4; ++ni) {
                acc[mi][ni] = __builtin_amdgcn_mfma_f32_16x16x32_bf16(ah[mi], bh[ni], acc[mi][ni], 0, 0, 0);
                acc[mi][ni] = __builtin_amdgcn_mfma_f32_16x16x32_bf16(ah[mi], bl[ni], acc[mi][ni], 0, 0, 0);
                acc[mi][ni] = __builtin_amdgcn_mfma_f32_16x16x32_bf16(al[mi], bh[ni], acc[mi][ni], 0, 0, 0);
            }
    }

    // epilogue: C/D layout col=lane&15, row=(lane>>4)*4+reg
#pragma unroll
    for (int ni = 0; ni < 4; ++ni) {
        int col = col0 + wn * 64 + ni * 16 + l15;
        float bv = bias[col];
        float sc = 0.f, sh = 0.f;
        if constexpr (OUTM == 2) { sc = scl[col]; sh = shf[col]; }
#pragma unroll
        for (int mi = 0; mi < 4; ++mi) {
#pragma unroll
            for (int r = 0; r < 4; ++r) {
                int row = row0 + wm * 64 + mi * 16 + l4 * 4 + r;
                if (row < M) {
                    float v = acc[mi][ni][r] + bv;
                    if constexpr (OUTM == 2) v = fmaf(v, sc, sh);
                    v = fmaxf(v, 0.f);
                    Cp[(size_t)row * N + col] = packsplit(v);
                }
            }
        }
    }
}

// ---------------- Global add pool ------------------------------------------
__device__ __forceinline__ int lower_bound_i(const int* a, int n, int key) {
    int lo = 0, hi = n;
    while (lo < hi) {
        int mid = (lo + hi) >> 1;
        if (a[mid] < key) lo = mid + 1; else hi = mid;
    }
    return lo;
}

__global__ __launch_bounds__(256) void pool_k(
    const uint32* __restrict__ Hp, const int* __restrict__ batch,
    float* __restrict__ out)
{
    int g = blockIdx.x;
    int col = threadIdx.x;
    int lo = lower_bound_i(batch, NN, g);
    int hi = lower_bound_i(batch, NN, g + 1);
    float acc = 0.f;
    for (int n = lo; n < hi; ++n) acc += unpacksplit(Hp[(size_t)n * DD + col]);
    out[(size_t)g * DD + col] = acc;
}

// ---------------------------------------------------------------------------
extern "C" void kernel_launch(void* const* d_in, const int* in_sizes, int n_in,
                              void* d_out, int out_size, void* d_ws, size_t ws_size,
                              hipStream_t stream)
{
    const int*   x        = (const int*)d_in[0];
    const int*   ei       = (const int*)d_in[1];
    const int*   ea       = (const int*)d_in[2];
    const int*   batch    = (const int*)d_in[3];
    const float* atom_emb = (const float*)d_in[4];
    const float* bond1    = (const float*)d_in[5];
    const float* bond2    = (const float*)d_in[6];
    const float* c1_w1    = (const float*)d_in[7];
    const float* c1_b1    = (const float*)d_in[8];
    const float* c1_g     = (const float*)d_in[9];
    const float* c1_be    = (const float*)d_in[10];
    const float* c1_w2    = (const float*)d_in[11];
    const float* c1_b2    = (const float*)d_in[12];
    const float* c2_w1    = (const float*)d_in[13];
    const float* c2_b1    = (const float*)d_in[14];
    const float* c2_g     = (const float*)d_in[15];
    const float* c2_be    = (const float*)d_in[16];
    const float* c2_w2    = (const float*)d_in[17];
    const float* c2_b2    = (const float*)d_in[18];
    float* out = (float*)d_out;

    // ---- workspace layout ----
    uint32* Hp   = (uint32*)d_ws;                      // [NN,256] packed
    uint32* Zp   = Hp + (size_t)NN * DD;               // [NN,256] packed
    float*  G    = (float*)(Zp + (size_t)NN * DD);     // [256,256]
    float*  cs   = G + 65536;                          // [256]
    float*  scl  = cs + 256;                           // [512]
    float*  shf  = scl + 512;                          // [512]
    float*  bcomb = shf + 512;                         // [1000,256]
    uint32* W1p = (uint32*)(bcomb + 1000 * DD);        // [256,512]
    uint32* W2p = W1p + 256 * 512;                     // [512,256]
    uint32* W3p = W2p + 512 * 256;                     // [256,256]
    uint32* W4p = W3p + 256 * 256;                     // [256,256]
    int* cnt    = (int*)(W4p + 256 * 256);             // [SCAN_N]
    int* rs     = cnt + SCAN_N;                        // [SCAN_N]
    int* bsum   = rs + SCAN_N;                         // [512]
    int* boff   = bsum + 512;                          // [512]
    int* cursor = boff + 512;                          // [NN]
    int* meta   = cursor + NN;                         // [NE]
    uint32* ystrip = (uint32*)(meta + NE);             // [strip,512] packed

    size_t fixed_bytes = (size_t)((char*)ystrip - (char*)d_ws);
    size_t avail = ws_size > fixed_bytes ? ws_size - fixed_bytes : 0;
    int strip = (int)(avail / (512 * sizeof(uint32)));
    strip = (strip / 128) * 128;
    if (strip > 25600) strip = 25600;
    if (strip < 128) strip = 128;

    const int eb = (NE + 255) / 256;

    zero_k<<<(SCAN_N + 255) / 256, 256, 0, stream>>>((float*)cnt, SCAN_N);
    zero_k<<<(65792 + 255) / 256, 256, 0, stream>>>(G, 65792);   // G + cs

    // weight packs (once per call)
    packmat_k<<<512, 256, 0, stream>>>(c1_w1, W1p, 256 * 512);
    packmat_k<<<512, 256, 0, stream>>>(c1_w2, W2p, 512 * 256);
    packmat_k<<<256, 256, 0, stream>>>(c2_w1, W3p, 256 * 256);
    packmat_k<<<256, 256, 0, stream>>>(c2_w2, W4p, 256 * 256);

    atom_embed_k<<<NN / 4, 256, 0, stream>>>(x, atom_emb, Hp);

    // CSR build (conv-invariant)
    hist_k<<<eb, 256, 0, stream>>>(ei, cnt);
    scan1_k<<<SCAN_B, 256, 0, stream>>>(cnt, bsum);
    scan2_k<<<1, 512, 0, stream>>>(bsum, boff);
    scan3_k<<<SCAN_B, 256, 0, stream>>>(cnt, boff, rs, cursor);
    scatter_k<<<eb, 256, 0, stream>>>(ei, ea, cursor, meta);

    // ================= conv1 =================
    bcomb_k<<<1000, 256, 0, stream>>>(bond1, bcomb);
    gather_agg_k<<<NN / 4, 256, 0, stream>>>(Hp, bcomb, rs, meta, Zp);
    gram_k<<<4 * NGCH, 256, 0, stream>>>(Zp, G);
    colsum_k<<<SCAN_B, 256, 0, stream>>>(Zp, cs);
    bnprep_k<<<512, 256, 0, stream>>>(G, cs, c1_w1, c1_b1, c1_g, c1_be, scl, shf, 512);
    for (int r0 = 0; r0 < NN; r0 += strip) {
        int Ms = (NN - r0 < strip) ? NN - r0 : strip;
        int mt = (Ms + 127) / 128;
        gemm_mfma_k<2><<<mt * 4, 256, 0, stream>>>(
            Zp + (size_t)r0 * DD, W1p, c1_b1, ystrip, Ms, 512, 256, scl, shf);
        gemm_mfma_k<1><<<mt * 2, 256, 0, stream>>>(
            ystrip, W2p, c1_b2, Hp + (size_t)r0 * DD, Ms, 256, 512, nullptr, nullptr);
    }

    // ================= conv2 =================
    zero_k<<<(65792 + 255) / 256, 256, 0, stream>>>(G, 65792);
    bcomb_k<<<1000, 256, 0, stream>>>(bond2, bcomb);
    gather_agg_k<<<NN / 4, 256, 0, stream>>>(Hp, bcomb, rs, meta, Zp);
    gram_k<<<4 * NGCH, 256, 0, stream>>>(Zp, G);
    colsum_k<<<SCAN_B, 256, 0, stream>>>(Zp, cs);
    bnprep_k<<<256, 256, 0, stream>>>(G, cs, c2_w1, c2_b1, c2_g, c2_be, scl, shf, 256);
    for (int r0 = 0; r0 < NN; r0 += strip) {
        int Ms = (NN - r0 < strip) ? NN - r0 : strip;
        int mt = (Ms + 127) / 128;
        gemm_mfma_k<2><<<mt * 2, 256, 0, stream>>>(
            Zp + (size_t)r0 * DD, W3p, c2_b1, ystrip, Ms, 256, 256, scl, shf);
        gemm_mfma_k<1><<<mt * 2, 256, 0, stream>>>(
            ystrip, W4p, c2_b2, Hp + (size_t)r0 * DD, Ms, 256, 256, nullptr, nullptr);
    }

    // ---- pool ----
    pool_k<<<NG, 256, 0, stream>>>(Hp, batch, out);
}

// Round 6
// 2485.777 us; speedup vs baseline: 1.7608x; 1.2171x over previous
//
#include <hip/hip_runtime.h>

#define NN 100000
#define NE 3200000
#define NG 2048
#define DD 256
#define EPSV 1e-5f
#define SCAN_N 100096           // 391 * 256 >= NN+1
#define SCAN_B 391
#define GCH 1568                // gram split-K chunk rows
#define NGCH 64

typedef unsigned int uint32;
typedef __attribute__((ext_vector_type(2))) unsigned int uivec2;
typedef __attribute__((ext_vector_type(4))) unsigned int uivec4;
typedef __attribute__((ext_vector_type(4))) float f32x4;
typedef __attribute__((ext_vector_type(8))) short short8_t;

__device__ __forceinline__ float4 ld4(const float* p) {
    return *reinterpret_cast<const float4*>(p);
}
__device__ __forceinline__ void st4(float* p, float4 v) {
    *reinterpret_cast<float4*>(p) = v;
}
__device__ __forceinline__ uivec4 ldu4(const uint32* p) {
    return *reinterpret_cast<const uivec4*>(p);
}

// ---- packed split-bf16: u = hi | (lo<<16); x ~= f32(hi<<16) + f32(lo<<16) --
__device__ __forceinline__ uint32 packsplit(float x) {
    uint32 u = __float_as_uint(x);
    uint32 hb = u >> 16;
    float hf = __uint_as_float(hb << 16);
    float lo = x - hf;
    uint32 lb = __float_as_uint(lo) >> 16;
    return hb | (lb << 16);
}
__device__ __forceinline__ float unpacksplit(uint32 u) {
    return __uint_as_float(u << 16) + __uint_as_float(u & 0xffff0000u);
}

// ---------------- zero fill ------------------------------------------------
__global__ __launch_bounds__(256) void zero_k(float* __restrict__ p, int n) {
    int i = blockIdx.x * 256 + threadIdx.x;
    if (i < n) p[i] = 0.f;
}

// ---------------- pack a f32 matrix into split form ------------------------
__global__ __launch_bounds__(256) void packmat_k(const float* __restrict__ X,
                                                 uint32* __restrict__ Xp, int n) {
    int i = blockIdx.x * 256 + threadIdx.x;
    if (i < n) Xp[i] = packsplit(X[i]);
}

// ---------------- Atom encoder (writes packed H) ---------------------------
__global__ __launch_bounds__(256) void atom_embed_k(
    const int* __restrict__ x, const float* __restrict__ emb,
    uint32* __restrict__ Hp)
{
    int lane = threadIdx.x & 63;
    int n = blockIdx.x * 4 + (threadIdx.x >> 6);
    if (n >= NN) return;
    int c4 = lane * 4;
    float4 acc = make_float4(0.f, 0.f, 0.f, 0.f);
#pragma unroll
    for (int c = 0; c < 9; ++c) {
        int idx = x[n * 9 + c];
        float4 v = ld4(emb + (size_t)(c * 100 + idx) * DD + c4);
        acc.x += v.x; acc.y += v.y; acc.z += v.z; acc.w += v.w;
    }
    uivec4 o;
    o[0] = packsplit(acc.x); o[1] = packsplit(acc.y);
    o[2] = packsplit(acc.z); o[3] = packsplit(acc.w);
    *reinterpret_cast<uivec4*>(Hp + (size_t)n * DD + c4) = o;
}

// ---------------- bond combo table (f32) -----------------------------------
__global__ __launch_bounds__(256) void bcomb_k(const float* __restrict__ bond,
                                               float* __restrict__ bcomb)
{
    int combo = blockIdx.x;          // 0..999
    int col = threadIdx.x;
    int b0 = combo % 10, b1 = (combo / 10) % 10, b2 = combo / 100;
    bcomb[(size_t)combo * DD + col] =
        bond[(size_t)b0 * DD + col] +
        bond[(size_t)(10 + b1) * DD + col] +
        bond[(size_t)(20 + b2) * DD + col];
}

// ---------------- CSR build ------------------------------------------------
__global__ __launch_bounds__(256) void hist_k(const int* __restrict__ ei,
                                              int* __restrict__ cnt)
{
    int e = blockIdx.x * 256 + threadIdx.x;
    if (e < NE) atomicAdd(&cnt[ei[NE + e]], 1);
}

__global__ __launch_bounds__(256) void scan1_k(int* __restrict__ cnt,
                                               int* __restrict__ bsum)
{
    __shared__ int s[2][256];
    int t = threadIdx.x;
    int i = blockIdx.x * 256 + t;
    int v = cnt[i];
    s[0][t] = v;
    __syncthreads();
    int p = 0;
    for (int off = 1; off < 256; off <<= 1) {
        int xv = s[p][t];
        if (t >= off) xv += s[p][t - off];
        s[p ^ 1][t] = xv;
        p ^= 1;
        __syncthreads();
    }
    int inc = s[p][t];
    cnt[i] = inc - v;
    if (t == 255) bsum[blockIdx.x] = inc;
}

__global__ __launch_bounds__(512) void scan2_k(const int* __restrict__ bsum,
                                               int* __restrict__ boff)
{
    __shared__ int s[2][512];
    int t = threadIdx.x;
    int v = (t < SCAN_B) ? bsum[t] : 0;
    s[0][t] = v;
    __syncthreads();
    int p = 0;
    for (int off = 1; off < 512; off <<= 1) {
        int xv = s[p][t];
        if (t >= off) xv += s[p][t - off];
        s[p ^ 1][t] = xv;
        p ^= 1;
        __syncthreads();
    }
    boff[t] = s[p][t] - v;
}

__global__ __launch_bounds__(256) void scan3_k(const int* __restrict__ cnt,
                                               const int* __restrict__ boff,
                                               int* __restrict__ rs,
                                               int* __restrict__ cursor)
{
    int i = blockIdx.x * 256 + threadIdx.x;
    int v = cnt[i] + boff[blockIdx.x];
    rs[i] = v;
    if (i < NN) cursor[i] = v;
}

__global__ __launch_bounds__(256) void scatter_k(const int* __restrict__ ei,
                                                 const int* __restrict__ ea,
                                                 int* __restrict__ cursor,
                                                 int* __restrict__ meta)
{
    int e = blockIdx.x * 256 + threadIdx.x;
    if (e >= NE) return;
    int src = ei[e];
    int dst = ei[NE + e];
    int combo = ea[e * 3 + 0] + 10 * ea[e * 3 + 1] + 100 * ea[e * 3 + 2];
    int pos = atomicAdd(&cursor[dst], 1);
    meta[pos] = (src << 10) | combo;
}

// ---------------- Gather-aggregate, column-split halves --------------------
// Each pass covers 128 of the 256 cols => per-pass working set ~115 MB (L3-fit)
__device__ __forceinline__ void edge_acc2(const uint32* __restrict__ Hp,
                                          const float* __restrict__ bcomb,
                                          int m, int c2, float& ax, float& ay)
{
    uivec2 v = *reinterpret_cast<const uivec2*>(Hp + (size_t)(m >> 10) * DD + c2);
    float2 b = *reinterpret_cast<const float2*>(bcomb + (size_t)(m & 1023) * DD + c2);
    ax += fmaxf(unpacksplit(v[0]) + b.x, 0.f);
    ay += fmaxf(unpacksplit(v[1]) + b.y, 0.f);
}

__global__ __launch_bounds__(256) void gather_half_k(
    const uint32* __restrict__ Hp, const float* __restrict__ bcomb,
    const int* __restrict__ rs, const int* __restrict__ meta,
    uint32* __restrict__ Zp, int colbase)
{
    int lane = threadIdx.x & 63;
    int n = blockIdx.x * 4 + (threadIdx.x >> 6);
    if (n >= NN) return;
    int c2 = colbase + lane * 2;
    uivec2 hu = *reinterpret_cast<const uivec2*>(Hp + (size_t)n * DD + c2);
    float ax = unpacksplit(hu[0]), ay = unpacksplit(hu[1]);
    int lo = rs[n], hi = rs[n + 1];
    int t = lo;
    for (; t + 4 <= hi; t += 4) {
        int m0 = meta[t], m1 = meta[t + 1], m2 = meta[t + 2], m3 = meta[t + 3];
        edge_acc2(Hp, bcomb, m0, c2, ax, ay);
        edge_acc2(Hp, bcomb, m1, c2, ax, ay);
        edge_acc2(Hp, bcomb, m2, c2, ax, ay);
        edge_acc2(Hp, bcomb, m3, c2, ax, ay);
    }
    for (; t < hi; ++t)
        edge_acc2(Hp, bcomb, meta[t], c2, ax, ay);
    uivec2 z;
    z[0] = packsplit(ax); z[1] = packsplit(ay);
    *reinterpret_cast<uivec2*>(Zp + (size_t)n * DD + c2) = z;
}

// ---------------- MFMA Gram: G += Z^T Z (split-bf16, split-K atomics) ------
// Block = 128x128 tile of G; 4 waves (2x2 of 64x64); K = 32 Z-rows per step.
// A and B fragments use the SAME k-slot mapping -> pairing is permutation-safe.
__global__ __launch_bounds__(256) void gram_mfma_k(const uint32* __restrict__ Zp,
                                                   float* __restrict__ G)
{
    __shared__ uint32 Ta[32][130];
    __shared__ uint32 Tb[32][130];
    const int tid = threadIdx.x;
    const int lane = tid & 63;
    const int l15 = lane & 15;
    const int l4 = lane >> 4;
    const int wave = tid >> 6;
    const int wm = wave >> 1, wn = wave & 1;
    const int bj = blockIdx.x & 1;
    const int bi = (blockIdx.x >> 1) & 1;
    const int ch = blockIdx.x >> 2;
    const int rbase = ch * GCH;

    f32x4 acc[4][4] = {};

    for (int kt = 0; kt < GCH; kt += 32) {
        __syncthreads();
#pragma unroll
        for (int i = 0; i < 4; ++i) {
            int f = i * 256 + tid;
            int row = f >> 5, cq = f & 31;
            int r = rbase + kt + row;
            uivec4 a = {0, 0, 0, 0}, b = {0, 0, 0, 0};
            if (r < NN) {
                a = ldu4(Zp + (size_t)r * DD + bi * 128 + cq * 4);
                b = ldu4(Zp + (size_t)r * DD + bj * 128 + cq * 4);
            }
            *reinterpret_cast<uivec4*>(&Ta[row][cq * 4]) = a;
            *reinterpret_cast<uivec4*>(&Tb[row][cq * 4]) = b;
        }
        __syncthreads();

        short8_t ah[4], al[4], bh[4], bl[4];
#pragma unroll
        for (int mi = 0; mi < 4; ++mi) {
            int ci = wm * 64 + mi * 16 + l15;
            short8_t h, l;
#pragma unroll
            for (int j = 0; j < 8; ++j) {
                uint32 u = Ta[l4 * 8 + j][ci];
                h[j] = (short)(u & 0xffff);
                l[j] = (short)(u >> 16);
            }
            ah[mi] = h; al[mi] = l;
        }
#pragma unroll
        for (int ni = 0; ni < 4; ++ni) {
            int ci = wn * 64 + ni * 16 + l15;
            short8_t h, l;
#pragma unroll
            for (int j = 0; j < 8; ++j) {
                uint32 u = Tb[l4 * 8 + j][ci];
                h[j] = (short)(u & 0xffff);
                l[j] = (short)(u >> 16);
            }
            bh[ni] = h; bl[ni] = l;
        }
#pragma unroll
        for (int mi = 0; mi < 4; ++mi)
#pragma unroll
            for (int ni = 0; ni < 4; ++ni) {
                acc[mi][ni] = __builtin_amdgcn_mfma_f32_16x16x32_bf16(ah[mi], bh[ni], acc[mi][ni], 0, 0, 0);
                acc[mi][ni] = __builtin_amdgcn_mfma_f32_16x16x32_bf16(ah[mi], bl[ni], acc[mi][ni], 0, 0, 0);
                acc[mi][ni] = __builtin_amdgcn_mfma_f32_16x16x32_bf16(al[mi], bh[ni], acc[mi][ni], 0, 0, 0);
            }
    }

#pragma unroll
    for (int mi = 0; mi < 4; ++mi) {
#pragma unroll
        for (int ni = 0; ni < 4; ++ni) {
            int col = bj * 128 + wn * 64 + ni * 16 + l15;
#pragma unroll
            for (int r = 0; r < 4; ++r) {
                int row = bi * 128 + wm * 64 + mi * 16 + l4 * 4 + r;
                atomicAdd(&G[row * 256 + col], acc[mi][ni][r]);
            }
        }
    }
}

// ---------------- column sums ---------------------------------------------
__global__ __launch_bounds__(256) void colsum_k(const uint32* __restrict__ Zp,
                                                float* __restrict__ cs)
{
    int t = threadIdx.x;
    int r0 = blockIdx.x * 256;
    int r1 = r0 + 256 < NN ? r0 + 256 : NN;
    float acc = 0.f;
    for (int r = r0; r < r1; ++r) acc += unpacksplit(Zp[(size_t)r * DD + t]);
    atomicAdd(&cs[t], acc);
}

// ---------------- BN prep from Gram (f64 finalize) -------------------------
__global__ __launch_bounds__(256) void bnprep_k(
    const float* __restrict__ G, const float* __restrict__ cs,
    const float* __restrict__ W, const float* __restrict__ b,
    const float* __restrict__ g, const float* __restrict__ be,
    float* __restrict__ scl, float* __restrict__ shf, int N)
{
    __shared__ float wv[256];
    __shared__ double r1[256];
    __shared__ double r2[256];
    int c = blockIdx.x;
    int t = threadIdx.x;
    wv[t] = W[t * N + c];
    __syncthreads();
    double gd = 0.0;
    const float* Gr = G + t * 256;
    for (int j = 0; j < 256; ++j) gd += (double)Gr[j] * (double)wv[j];
    r1[t] = (double)wv[t] * gd;
    r2[t] = (double)cs[t] * (double)wv[t];
    __syncthreads();
    for (int off = 128; off > 0; off >>= 1) {
        if (t < off) { r1[t] += r1[t + off]; r2[t] += r2[t + off]; }
        __syncthreads();
    }
    if (t == 0) {
        double szw = r2[0];
        double s2zw = r1[0];
        double bb = (double)b[c];
        double fN = (double)NN;
        double S1 = szw + fN * bb;
        double S2 = s2zw + 2.0 * bb * szw + fN * bb * bb;
        double mu = S1 / fN;
        double var = S2 / fN - mu * mu;
        float s = g[c] * rsqrtf((float)var + EPSV);
        scl[c] = s;
        shf[c] = be[c] - (float)mu * s;
    }
}

// ---------------- split-bf16 MFMA GEMM -------------------------------------
// C = relu([BN](A @ W + bias)); A, W, C all packed-split uint32.
// 128x128 tile, 4 waves (2x2 of 64x64), BK=32, 3 MFMA products (hh, hl, lh).
template <int OUTM>
__global__ __launch_bounds__(256) void gemm_mfma_k(
    const uint32* __restrict__ Ap, const uint32* __restrict__ Wp,
    const float* __restrict__ bias, uint32* __restrict__ Cp,
    int M, int N, int K,
    const float* __restrict__ scl, const float* __restrict__ shf)
{
    __shared__ uint32 As[128][36];

    const int tid = threadIdx.x;
    const int lane = tid & 63;
    const int l15 = lane & 15;
    const int l4 = lane >> 4;
    const int wave = tid >> 6;
    const int wm = wave >> 1, wn = wave & 1;
    const int ntx = N / 128;
    const int bx = blockIdx.x % ntx;
    const int by = blockIdx.x / ntx;
    const int row0 = by * 128, col0 = bx * 128;

    f32x4 acc[4][4] = {};

    for (int kt = 0; kt < K; kt += 32) {
        __syncthreads();
#pragma unroll
        for (int i = 0; i < 4; ++i) {
            int f = i * 256 + tid;
            int row = f >> 3, q = f & 7;
            int r = row0 + row;
            if (r >= M) r = M - 1;
            *reinterpret_cast<uivec4*>(&As[row][q * 4]) =
                ldu4(Ap + (size_t)r * K + kt + q * 4);
        }
        __syncthreads();

        short8_t ah[4], al[4];
#pragma unroll
        for (int mi = 0; mi < 4; ++mi) {
            int m = wm * 64 + mi * 16 + l15;
            uivec4 u0 = *reinterpret_cast<const uivec4*>(&As[m][l4 * 8]);
            uivec4 u1 = *reinterpret_cast<const uivec4*>(&As[m][l4 * 8 + 4]);
            short8_t h, l;
#pragma unroll
            for (int j = 0; j < 4; ++j) {
                h[j] = (short)(u0[j] & 0xffff);
                l[j] = (short)(u0[j] >> 16);
                h[4 + j] = (short)(u1[j] & 0xffff);
                l[4 + j] = (short)(u1[j] >> 16);
            }
            ah[mi] = h; al[mi] = l;
        }
        short8_t bh[4], bl[4];
#pragma unroll
        for (int ni = 0; ni < 4; ++ni) {
            int col = col0 + wn * 64 + ni * 16 + l15;
            const uint32* wp = Wp + (size_t)(kt + l4 * 8) * N + col;
            short8_t h, l;
#pragma unroll
            for (int j = 0; j < 8; ++j) {
                uint32 u = wp[(size_t)j * N];
                h[j] = (short)(u & 0xffff);
                l[j] = (short)(u >> 16);
            }
            bh[ni] = h; bl[ni] = l;
        }
#pragma unroll
        for (int mi = 0; mi < 4; ++mi)
#pragma unroll
            for (int ni = 0; ni < 4; ++ni) {
                acc[mi][ni] = __builtin_amdgcn_mfma_f32_16x16x32_bf16(ah[mi], bh[ni], acc[mi][ni], 0, 0, 0);
                acc[mi][ni] = __builtin_amdgcn_mfma_f32_16x16x32_bf16(ah[mi], bl[ni], acc[mi][ni], 0, 0, 0);
                acc[mi][ni] = __builtin_amdgcn_mfma_f32_16x16x32_bf16(al[mi], bh[ni], acc[mi][ni], 0, 0, 0);
            }
    }

    // epilogue: C/D layout col=lane&15, row=(lane>>4)*4+reg
#pragma unroll
    for (int ni = 0; ni < 4; ++ni) {
        int col = col0 + wn * 64 + ni * 16 + l15;
        float bv = bias[col];
        float sc = 0.f, sh = 0.f;
        if constexpr (OUTM == 2) { sc = scl[col]; sh = shf[col]; }
#pragma unroll
        for (int mi = 0; mi < 4; ++mi) {
#pragma unroll
            for (int r = 0; r < 4; ++r) {
                int row = row0 + wm * 64 + mi * 16 + l4 * 4 + r;
                if (row < M) {
                    float v = acc[mi][ni][r] + bv;
                    if constexpr (OUTM == 2) v = fmaf(v, sc, sh);
                    v = fmaxf(v, 0.f);
                    Cp[(size_t)row * N + col] = packsplit(v);
                }
            }
        }
    }
}

// ---------------- Global add pool ------------------------------------------
__device__ __forceinline__ int lower_bound_i(const int* a, int n, int key) {
    int lo = 0, hi = n;
    while (lo < hi) {
        int mid = (lo + hi) >> 1;
        if (a[mid] < key) lo = mid + 1; else hi = mid;
    }
    return lo;
}

__global__ __launch_bounds__(256) void pool_k(
    const uint32* __restrict__ Hp, const int* __restrict__ batch,
    float* __restrict__ out)
{
    int g = blockIdx.x;
    int col = threadIdx.x;
    int lo = lower_bound_i(batch, NN, g);
    int hi = lower_bound_i(batch, NN, g + 1);
    float acc = 0.f;
    for (int n = lo; n < hi; ++n) acc += unpacksplit(Hp[(size_t)n * DD + col]);
    out[(size_t)g * DD + col] = acc;
}

// ---------------------------------------------------------------------------
extern "C" void kernel_launch(void* const* d_in, const int* in_sizes, int n_in,
                              void* d_out, int out_size, void* d_ws, size_t ws_size,
                              hipStream_t stream)
{
    const int*   x        = (const int*)d_in[0];
    const int*   ei       = (const int*)d_in[1];
    const int*   ea       = (const int*)d_in[2];
    const int*   batch    = (const int*)d_in[3];
    const float* atom_emb = (const float*)d_in[4];
    const float* bond1    = (const float*)d_in[5];
    const float* bond2    = (const float*)d_in[6];
    const float* c1_w1    = (const float*)d_in[7];
    const float* c1_b1    = (const float*)d_in[8];
    const float* c1_g     = (const float*)d_in[9];
    const float* c1_be    = (const float*)d_in[10];
    const float* c1_w2    = (const float*)d_in[11];
    const float* c1_b2    = (const float*)d_in[12];
    const float* c2_w1    = (const float*)d_in[13];
    const float* c2_b1    = (const float*)d_in[14];
    const float* c2_g     = (const float*)d_in[15];
    const float* c2_be    = (const float*)d_in[16];
    const float* c2_w2    = (const float*)d_in[17];
    const float* c2_b2    = (const float*)d_in[18];
    float* out = (float*)d_out;

    // ---- workspace layout ----
    uint32* Hp   = (uint32*)d_ws;                      // [NN,256] packed
    uint32* Zp   = Hp + (size_t)NN * DD;               // [NN,256] packed
    float*  G    = (float*)(Zp + (size_t)NN * DD);     // [256,256]
    float*  cs   = G + 65536;                          // [256]
    float*  scl  = cs + 256;                           // [512]
    float*  shf  = scl + 512;                          // [512]
    float*  bcomb = shf + 512;                         // [1000,256]
    uint32* W1p = (uint32*)(bcomb + 1000 * DD);        // [256,512]
    uint32* W2p = W1p + 256 * 512;                     // [512,256]
    uint32* W3p = W2p + 512 * 256;                     // [256,256]
    uint32* W4p = W3p + 256 * 256;                     // [256,256]
    int* cnt    = (int*)(W4p + 256 * 256);             // [SCAN_N]
    int* rs     = cnt + SCAN_N;                        // [SCAN_N]
    int* bsum   = rs + SCAN_N;                         // [512]
    int* boff   = bsum + 512;                          // [512]
    int* cursor = boff + 512;                          // [NN]
    int* meta   = cursor + NN;                         // [NE]
    uint32* ystrip = (uint32*)(meta + NE);             // [strip,512] packed

    size_t fixed_bytes = (size_t)((char*)ystrip - (char*)d_ws);
    size_t avail = ws_size > fixed_bytes ? ws_size - fixed_bytes : 0;
    int strip = (int)(avail / (512 * sizeof(uint32)));
    strip = (strip / 128) * 128;
    if (strip > 25600) strip = 25600;
    if (strip < 128) strip = 128;

    const int eb = (NE + 255) / 256;

    zero_k<<<(SCAN_N + 255) / 256, 256, 0, stream>>>((float*)cnt, SCAN_N);
    zero_k<<<(65792 + 255) / 256, 256, 0, stream>>>(G, 65792);   // G + cs

    // weight packs (once per call)
    packmat_k<<<512, 256, 0, stream>>>(c1_w1, W1p, 256 * 512);
    packmat_k<<<512, 256, 0, stream>>>(c1_w2, W2p, 512 * 256);
    packmat_k<<<256, 256, 0, stream>>>(c2_w1, W3p, 256 * 256);
    packmat_k<<<256, 256, 0, stream>>>(c2_w2, W4p, 256 * 256);

    atom_embed_k<<<NN / 4, 256, 0, stream>>>(x, atom_emb, Hp);

    // CSR build (conv-invariant)
    hist_k<<<eb, 256, 0, stream>>>(ei, cnt);
    scan1_k<<<SCAN_B, 256, 0, stream>>>(cnt, bsum);
    scan2_k<<<1, 512, 0, stream>>>(bsum, boff);
    scan3_k<<<SCAN_B, 256, 0, stream>>>(cnt, boff, rs, cursor);
    scatter_k<<<eb, 256, 0, stream>>>(ei, ea, cursor, meta);

    // ================= conv1 =================
    bcomb_k<<<1000, 256, 0, stream>>>(bond1, bcomb);
    gather_half_k<<<NN / 4, 256, 0, stream>>>(Hp, bcomb, rs, meta, Zp, 0);
    gather_half_k<<<NN / 4, 256, 0, stream>>>(Hp, bcomb, rs, meta, Zp, 128);
    gram_mfma_k<<<4 * NGCH, 256, 0, stream>>>(Zp, G);
    colsum_k<<<SCAN_B, 256, 0, stream>>>(Zp, cs);
    bnprep_k<<<512, 256, 0, stream>>>(G, cs, c1_w1, c1_b1, c1_g, c1_be, scl, shf, 512);
    for (int r0 = 0; r0 < NN; r0 += strip) {
        int Ms = (NN - r0 < strip) ? NN - r0 : strip;
        int mt = (Ms + 127) / 128;
        gemm_mfma_k<2><<<mt * 4, 256, 0, stream>>>(
            Zp + (size_t)r0 * DD, W1p, c1_b1, ystrip, Ms, 512, 256, scl, shf);
        gemm_mfma_k<1><<<mt * 2, 256, 0, stream>>>(
            ystrip, W2p, c1_b2, Hp + (size_t)r0 * DD, Ms, 256, 512, nullptr, nullptr);
    }

    // ================= conv2 =================
    zero_k<<<(65792 + 255) / 256, 256, 0, stream>>>(G, 65792);
    bcomb_k<<<1000, 256, 0, stream>>>(bond2, bcomb);
    gather_half_k<<<NN / 4, 256, 0, stream>>>(Hp, bcomb, rs, meta, Zp, 0);
    gather_half_k<<<NN / 4, 256, 0, stream>>>(Hp, bcomb, rs, meta, Zp, 128);
    gram_mfma_k<<<4 * NGCH, 256, 0, stream>>>(Zp, G);
    colsum_k<<<SCAN_B, 256, 0, stream>>>(Zp, cs);
    bnprep_k<<<256, 256, 0, stream>>>(G, cs, c2_w1, c2_b1, c2_g, c2_be, scl, shf, 256);
    for (int r0 = 0; r0 < NN; r0 += strip) {
        int Ms = (NN - r0 < strip) ? NN - r0 : strip;
        int mt = (Ms + 127) / 128;
        gemm_mfma_k<2><<<mt * 2, 256, 0, stream>>>(
            Zp + (size_t)r0 * DD, W3p, c2_b1, ystrip, Ms, 256, 256, scl, shf);
        gemm_mfma_k<1><<<mt * 2, 256, 0, stream>>>(
            ystrip, W4p, c2_b2, Hp + (size_t)r0 * DD, Ms, 256, 256, nullptr, nullptr);
    }

    // ---- pool ----
    pool_k<<<NG, 256, 0, stream>>>(Hp, batch, out);
}

// Round 7
// 2305.649 us; speedup vs baseline: 1.8983x; 1.0781x over previous
//
#include <hip/hip_runtime.h>

#define NN 100000
#define NE 3200000
#define NG 2048
#define DD 256
#define EPSV 1e-5f
#define SCAN_N 100096           // 391 * 256 >= NN+1
#define SCAN_B 391
#define GCH 1568                // gram split-K chunk rows
#define NGCH 64

typedef unsigned int uint32;
typedef unsigned short ushort16;
typedef __attribute__((ext_vector_type(4))) unsigned int uivec4;
typedef __attribute__((ext_vector_type(4))) unsigned short usvec4;
typedef __attribute__((ext_vector_type(4))) float f32x4;
typedef __attribute__((ext_vector_type(8))) short short8_t;

__device__ __forceinline__ float4 ld4(const float* p) {
    return *reinterpret_cast<const float4*>(p);
}
__device__ __forceinline__ float bf2f(ushort16 b) {
    return __uint_as_float((uint32)b << 16);
}

// ---- split-bf16: hi = RNE-bf16(x), lo = bf16(x - hi); u = hi | lo<<16 ------
__device__ __forceinline__ uint32 packsplit(float x) {
    uint32 u = __float_as_uint(x);
    uint32 hb = (u + 0x7fffu + ((u >> 16) & 1u)) >> 16;   // RNE
    float hf = __uint_as_float(hb << 16);
    float lo = x - hf;
    uint32 lb = __float_as_uint(lo) >> 16;
    return hb | (lb << 16);
}

// ---------------- zero fill ------------------------------------------------
__global__ __launch_bounds__(256) void zero_k(float* __restrict__ p, int n) {
    int i = blockIdx.x * 256 + threadIdx.x;
    if (i < n) p[i] = 0.f;
}

// ---------------- pack f32 weights into combined u32 split form ------------
__global__ __launch_bounds__(256) void packmat_k(const float* __restrict__ X,
                                                 uint32* __restrict__ Xp, int n) {
    int i = blockIdx.x * 256 + threadIdx.x;
    if (i < n) Xp[i] = packsplit(X[i]);
}

// ---------------- Atom encoder (writes H planes) ---------------------------
__global__ __launch_bounds__(256) void atom_embed_k(
    const int* __restrict__ x, const float* __restrict__ emb,
    ushort16* __restrict__ Hh, ushort16* __restrict__ Hl)
{
    int lane = threadIdx.x & 63;
    int n = blockIdx.x * 4 + (threadIdx.x >> 6);
    if (n >= NN) return;
    int c4 = lane * 4;
    float4 acc = make_float4(0.f, 0.f, 0.f, 0.f);
#pragma unroll
    for (int c = 0; c < 9; ++c) {
        int idx = x[n * 9 + c];
        float4 v = ld4(emb + (size_t)(c * 100 + idx) * DD + c4);
        acc.x += v.x; acc.y += v.y; acc.z += v.z; acc.w += v.w;
    }
    float a[4] = {acc.x, acc.y, acc.z, acc.w};
    usvec4 h, l;
#pragma unroll
    for (int j = 0; j < 4; ++j) {
        uint32 u = packsplit(a[j]);
        h[j] = (ushort16)(u & 0xffff);
        l[j] = (ushort16)(u >> 16);
    }
    *reinterpret_cast<usvec4*>(Hh + (size_t)n * DD + c4) = h;
    *reinterpret_cast<usvec4*>(Hl + (size_t)n * DD + c4) = l;
}

// ---------------- bond combo table (f32) -----------------------------------
__global__ __launch_bounds__(256) void bcomb_k(const float* __restrict__ bond,
                                               float* __restrict__ bcomb)
{
    int combo = blockIdx.x;          // 0..999
    int col = threadIdx.x;
    int b0 = combo % 10, b1 = (combo / 10) % 10, b2 = combo / 100;
    bcomb[(size_t)combo * DD + col] =
        bond[(size_t)b0 * DD + col] +
        bond[(size_t)(10 + b1) * DD + col] +
        bond[(size_t)(20 + b2) * DD + col];
}

// ---------------- CSR build ------------------------------------------------
__global__ __launch_bounds__(256) void hist_k(const int* __restrict__ ei,
                                              int* __restrict__ cnt)
{
    int e = blockIdx.x * 256 + threadIdx.x;
    if (e < NE) atomicAdd(&cnt[ei[NE + e]], 1);
}

__global__ __launch_bounds__(256) void scan1_k(int* __restrict__ cnt,
                                               int* __restrict__ bsum)
{
    __shared__ int s[2][256];
    int t = threadIdx.x;
    int i = blockIdx.x * 256 + t;
    int v = cnt[i];
    s[0][t] = v;
    __syncthreads();
    int p = 0;
    for (int off = 1; off < 256; off <<= 1) {
        int xv = s[p][t];
        if (t >= off) xv += s[p][t - off];
        s[p ^ 1][t] = xv;
        p ^= 1;
        __syncthreads();
    }
    int inc = s[p][t];
    cnt[i] = inc - v;
    if (t == 255) bsum[blockIdx.x] = inc;
}

__global__ __launch_bounds__(512) void scan2_k(const int* __restrict__ bsum,
                                               int* __restrict__ boff)
{
    __shared__ int s[2][512];
    int t = threadIdx.x;
    int v = (t < SCAN_B) ? bsum[t] : 0;
    s[0][t] = v;
    __syncthreads();
    int p = 0;
    for (int off = 1; off < 512; off <<= 1) {
        int xv = s[p][t];
        if (t >= off) xv += s[p][t - off];
        s[p ^ 1][t] = xv;
        p ^= 1;
        __syncthreads();
    }
    boff[t] = s[p][t] - v;
}

__global__ __launch_bounds__(256) void scan3_k(const int* __restrict__ cnt,
                                               const int* __restrict__ boff,
                                               int* __restrict__ rs,
                                               int* __restrict__ cursor)
{
    int i = blockIdx.x * 256 + threadIdx.x;
    int v = cnt[i] + boff[blockIdx.x];
    rs[i] = v;
    if (i < NN) cursor[i] = v;
}

__global__ __launch_bounds__(256) void scatter_k(const int* __restrict__ ei,
                                                 const int* __restrict__ ea,
                                                 int* __restrict__ cursor,
                                                 int* __restrict__ meta)
{
    int e = blockIdx.x * 256 + threadIdx.x;
    if (e >= NE) return;
    int src = ei[e];
    int dst = ei[NE + e];
    int combo = ea[e * 3 + 0] + 10 * ea[e * 3 + 1] + 100 * ea[e * 3 + 2];
    int pos = atomicAdd(&cursor[dst], 1);
    meta[pos] = (src << 10) | combo;
}

// ---------------- Gather-aggregate: single pass, hi-plane source -----------
// per edge: 8B from Hh (4 bf16 cols) + 16B bcomb(f32, L2). Self term hi+lo.
__device__ __forceinline__ void edge_acc(const ushort16* __restrict__ Hh,
                                         const float* __restrict__ bcomb,
                                         int m, int c4,
                                         float& a0, float& a1, float& a2, float& a3)
{
    usvec4 v = *reinterpret_cast<const usvec4*>(Hh + (size_t)(m >> 10) * DD + c4);
    float4 b = ld4(bcomb + (size_t)(m & 1023) * DD + c4);
    a0 += fmaxf(bf2f(v[0]) + b.x, 0.f);
    a1 += fmaxf(bf2f(v[1]) + b.y, 0.f);
    a2 += fmaxf(bf2f(v[2]) + b.z, 0.f);
    a3 += fmaxf(bf2f(v[3]) + b.w, 0.f);
}

__global__ __launch_bounds__(256) void gather_full_k(
    const ushort16* __restrict__ Hh, const ushort16* __restrict__ Hl,
    const float* __restrict__ bcomb,
    const int* __restrict__ rs, const int* __restrict__ meta,
    ushort16* __restrict__ Zh, ushort16* __restrict__ Zl)
{
    int lane = threadIdx.x & 63;
    int n = blockIdx.x * 4 + (threadIdx.x >> 6);
    if (n >= NN) return;
    int c4 = lane * 4;
    usvec4 sh = *reinterpret_cast<const usvec4*>(Hh + (size_t)n * DD + c4);
    usvec4 sl = *reinterpret_cast<const usvec4*>(Hl + (size_t)n * DD + c4);
    float a0 = bf2f(sh[0]) + bf2f(sl[0]);
    float a1 = bf2f(sh[1]) + bf2f(sl[1]);
    float a2 = bf2f(sh[2]) + bf2f(sl[2]);
    float a3 = bf2f(sh[3]) + bf2f(sl[3]);
    int lo = rs[n], hi = rs[n + 1];
    int t = lo;
    for (; t + 4 <= hi; t += 4) {
        int m0 = meta[t], m1 = meta[t + 1], m2 = meta[t + 2], m3 = meta[t + 3];
        edge_acc(Hh, bcomb, m0, c4, a0, a1, a2, a3);
        edge_acc(Hh, bcomb, m1, c4, a0, a1, a2, a3);
        edge_acc(Hh, bcomb, m2, c4, a0, a1, a2, a3);
        edge_acc(Hh, bcomb, m3, c4, a0, a1, a2, a3);
    }
    for (; t < hi; ++t)
        edge_acc(Hh, bcomb, meta[t], c4, a0, a1, a2, a3);
    float a[4] = {a0, a1, a2, a3};
    usvec4 zh, zl;
#pragma unroll
    for (int j = 0; j < 4; ++j) {
        uint32 u = packsplit(a[j]);
        zh[j] = (ushort16)(u & 0xffff);
        zl[j] = (ushort16)(u >> 16);
    }
    *reinterpret_cast<usvec4*>(Zh + (size_t)n * DD + c4) = zh;
    *reinterpret_cast<usvec4*>(Zl + (size_t)n * DD + c4) = zl;
}

// ---------------- MFMA Gram: G += Z^T Z (planes -> packed LDS) -------------
__global__ __launch_bounds__(256) void gram_mfma_k(
    const ushort16* __restrict__ Zh, const ushort16* __restrict__ Zl,
    float* __restrict__ G)
{
    __shared__ uint32 Ta[32][130];
    __shared__ uint32 Tb[32][130];
    const int tid = threadIdx.x;
    const int lane = tid & 63;
    const int l15 = lane & 15;
    const int l4 = lane >> 4;
    const int wave = tid >> 6;
    const int wm = wave >> 1, wn = wave & 1;
    const int bj = blockIdx.x & 1;
    const int bi = (blockIdx.x >> 1) & 1;
    const int ch = blockIdx.x >> 2;
    const int rbase = ch * GCH;

    f32x4 acc[4][4] = {};

    for (int kt = 0; kt < GCH; kt += 32) {
        __syncthreads();
#pragma unroll
        for (int i = 0; i < 4; ++i) {
            int f = i * 256 + tid;
            int row = f >> 5, g4 = f & 31;      // 4-element group
            int r = rbase + kt + row;
            uivec4 pa = {0, 0, 0, 0}, pb = {0, 0, 0, 0};
            if (r < NN) {
                const ushort16* zh = Zh + (size_t)r * DD;
                const ushort16* zl = Zl + (size_t)r * DD;
                usvec4 ah_ = *reinterpret_cast<const usvec4*>(zh + bi * 128 + g4 * 4);
                usvec4 al_ = *reinterpret_cast<const usvec4*>(zl + bi * 128 + g4 * 4);
                usvec4 bh_ = *reinterpret_cast<const usvec4*>(zh + bj * 128 + g4 * 4);
                usvec4 bl_ = *reinterpret_cast<const usvec4*>(zl + bj * 128 + g4 * 4);
#pragma unroll
                for (int j = 0; j < 4; ++j) {
                    pa[j] = (uint32)ah_[j] | ((uint32)al_[j] << 16);
                    pb[j] = (uint32)bh_[j] | ((uint32)bl_[j] << 16);
                }
            }
            *reinterpret_cast<uivec4*>(&Ta[row][g4 * 4]) = pa;
            *reinterpret_cast<uivec4*>(&Tb[row][g4 * 4]) = pb;
        }
        __syncthreads();

        short8_t ah[4], al[4], bh[4], bl[4];
#pragma unroll
        for (int mi = 0; mi < 4; ++mi) {
            int ci = wm * 64 + mi * 16 + l15;
            short8_t h, l;
#pragma unroll
            for (int j = 0; j < 8; ++j) {
                uint32 u = Ta[l4 * 8 + j][ci];
                h[j] = (short)(u & 0xffff);
                l[j] = (short)(u >> 16);
            }
            ah[mi] = h; al[mi] = l;
        }
#pragma unroll
        for (int ni = 0; ni < 4; ++ni) {
            int ci = wn * 64 + ni * 16 + l15;
            short8_t h, l;
#pragma unroll
            for (int j = 0; j < 8; ++j) {
                uint32 u = Tb[l4 * 8 + j][ci];
                h[j] = (short)(u & 0xffff);
                l[j] = (short)(u >> 16);
            }
            bh[ni] = h; bl[ni] = l;
        }
#pragma unroll
        for (int mi = 0; mi < 4; ++mi)
#pragma unroll
            for (int ni = 0; ni < 4; ++ni) {
                acc[mi][ni] = __builtin_amdgcn_mfma_f32_16x16x32_bf16(ah[mi], bh[ni], acc[mi][ni], 0, 0, 0);
                acc[mi][ni] = __builtin_amdgcn_mfma_f32_16x16x32_bf16(ah[mi], bl[ni], acc[mi][ni], 0, 0, 0);
                acc[mi][ni] = __builtin_amdgcn_mfma_f32_16x16x32_bf16(al[mi], bh[ni], acc[mi][ni], 0, 0, 0);
            }
    }

#pragma unroll
    for (int mi = 0; mi < 4; ++mi) {
#pragma unroll
        for (int ni = 0; ni < 4; ++ni) {
            int col = bj * 128 + wn * 64 + ni * 16 + l15;
#pragma unroll
            for (int r = 0; r < 4; ++r) {
                int row = bi * 128 + wm * 64 + mi * 16 + l4 * 4 + r;
                atomicAdd(&G[row * 256 + col], acc[mi][ni][r]);
            }
        }
    }
}

// ---------------- column sums ---------------------------------------------
__global__ __launch_bounds__(256) void colsum_k(const ushort16* __restrict__ Zh,
                                                const ushort16* __restrict__ Zl,
                                                float* __restrict__ cs)
{
    int t = threadIdx.x;
    int r0 = blockIdx.x * 256;
    int r1 = r0 + 256 < NN ? r0 + 256 : NN;
    float acc = 0.f;
    for (int r = r0; r < r1; ++r)
        acc += bf2f(Zh[(size_t)r * DD + t]) + bf2f(Zl[(size_t)r * DD + t]);
    atomicAdd(&cs[t], acc);
}

// ---------------- BN prep from Gram (f64 finalize) -------------------------
__global__ __launch_bounds__(256) void bnprep_k(
    const float* __restrict__ G, const float* __restrict__ cs,
    const float* __restrict__ W, const float* __restrict__ b,
    const float* __restrict__ g, const float* __restrict__ be,
    float* __restrict__ scl, float* __restrict__ shf, int N)
{
    __shared__ float wv[256];
    __shared__ double r1[256];
    __shared__ double r2[256];
    int c = blockIdx.x;
    int t = threadIdx.x;
    wv[t] = W[t * N + c];
    __syncthreads();
    double gd = 0.0;
    const float* Gr = G + t * 256;
    for (int j = 0; j < 256; ++j) gd += (double)Gr[j] * (double)wv[j];
    r1[t] = (double)wv[t] * gd;
    r2[t] = (double)cs[t] * (double)wv[t];
    __syncthreads();
    for (int off = 128; off > 0; off >>= 1) {
        if (t < off) { r1[t] += r1[t + off]; r2[t] += r2[t + off]; }
        __syncthreads();
    }
    if (t == 0) {
        double szw = r2[0];
        double s2zw = r1[0];
        double bb = (double)b[c];
        double fN = (double)NN;
        double S1 = szw + fN * bb;
        double S2 = s2zw + 2.0 * bb * szw + fN * bb * bb;
        double mu = S1 / fN;
        double var = S2 / fN - mu * mu;
        float s = g[c] * rsqrtf((float)var + EPSV);
        scl[c] = s;
        shf[c] = be[c] - (float)mu * s;
    }
}

// ---------------- split-bf16 MFMA GEMM (A planes, W packed, C planes) ------
// 128x128 tile, 4 waves (2x2 of 64x64), BK=32, 3 MFMA products.
template <int OUTM>
__global__ __launch_bounds__(256) void gemm_mfma_k(
    const ushort16* __restrict__ Ah, const ushort16* __restrict__ Al,
    const uint32* __restrict__ Wp, const float* __restrict__ bias,
    ushort16* __restrict__ Ch, ushort16* __restrict__ Cl,
    int M, int N, int K,
    const float* __restrict__ scl, const float* __restrict__ shf)
{
    __shared__ uint32 As[128][36];

    const int tid = threadIdx.x;
    const int lane = tid & 63;
    const int l15 = lane & 15;
    const int l4 = lane >> 4;
    const int wave = tid >> 6;
    const int wm = wave >> 1, wn = wave & 1;
    const int ntx = N / 128;
    const int bx = blockIdx.x % ntx;
    const int by = blockIdx.x / ntx;
    const int row0 = by * 128, col0 = bx * 128;

    f32x4 acc[4][4] = {};

    for (int kt = 0; kt < K; kt += 32) {
        __syncthreads();
        // stage A tile from planes, pack hi|lo<<16 into LDS
#pragma unroll
        for (int i = 0; i < 4; ++i) {
            int f = i * 256 + tid;
            int row = f >> 3, q = f & 7;         // 4-element group
            int r = row0 + row;
            if (r >= M) r = M - 1;
            usvec4 hh = *reinterpret_cast<const usvec4*>(Ah + (size_t)r * K + kt + q * 4);
            usvec4 ll = *reinterpret_cast<const usvec4*>(Al + (size_t)r * K + kt + q * 4);
            uivec4 pk;
#pragma unroll
            for (int j = 0; j < 4; ++j)
                pk[j] = (uint32)hh[j] | ((uint32)ll[j] << 16);
            *reinterpret_cast<uivec4*>(&As[row][q * 4]) = pk;
        }
        __syncthreads();

        short8_t ah[4], al[4];
#pragma unroll
        for (int mi = 0; mi < 4; ++mi) {
            int m = wm * 64 + mi * 16 + l15;
            uivec4 u0 = *reinterpret_cast<const uivec4*>(&As[m][l4 * 8]);
            uivec4 u1 = *reinterpret_cast<const uivec4*>(&As[m][l4 * 8 + 4]);
            short8_t h, l;
#pragma unroll
            for (int j = 0; j < 4; ++j) {
                h[j] = (short)(u0[j] & 0xffff);
                l[j] = (short)(u0[j] >> 16);
                h[4 + j] = (short)(u1[j] & 0xffff);
                l[4 + j] = (short)(u1[j] >> 16);
            }
            ah[mi] = h; al[mi] = l;
        }
        short8_t bh[4], bl[4];
#pragma unroll
        for (int ni = 0; ni < 4; ++ni) {
            int col = col0 + wn * 64 + ni * 16 + l15;
            const uint32* wp = Wp + (size_t)(kt + l4 * 8) * N + col;
            short8_t h, l;
#pragma unroll
            for (int j = 0; j < 8; ++j) {
                uint32 u = wp[(size_t)j * N];
                h[j] = (short)(u & 0xffff);
                l[j] = (short)(u >> 16);
            }
            bh[ni] = h; bl[ni] = l;
        }
#pragma unroll
        for (int mi = 0; mi < 4; ++mi)
#pragma unroll
            for (int ni = 0; ni < 4; ++ni) {
                acc[mi][ni] = __builtin_amdgcn_mfma_f32_16x16x32_bf16(ah[mi], bh[ni], acc[mi][ni], 0, 0, 0);
                acc[mi][ni] = __builtin_amdgcn_mfma_f32_16x16x32_bf16(ah[mi], bl[ni], acc[mi][ni], 0, 0, 0);
                acc[mi][ni] = __builtin_amdgcn_mfma_f32_16x16x32_bf16(al[mi], bh[ni], acc[mi][ni], 0, 0, 0);
            }
    }

    // epilogue: C/D layout col=lane&15, row=(lane>>4)*4+reg
#pragma unroll
    for (int ni = 0; ni < 4; ++ni) {
        int col = col0 + wn * 64 + ni * 16 + l15;
        float bv = bias[col];
        float sc = 0.f, sh = 0.f;
        if constexpr (OUTM == 2) { sc = scl[col]; sh = shf[col]; }
#pragma unroll
        for (int mi = 0; mi < 4; ++mi) {
#pragma unroll
            for (int r = 0; r < 4; ++r) {
                int row = row0 + wm * 64 + mi * 16 + l4 * 4 + r;
                if (row < M) {
                    float v = acc[mi][ni][r] + bv;
                    if constexpr (OUTM == 2) v = fmaf(v, sc, sh);
                    v = fmaxf(v, 0.f);
                    uint32 u = packsplit(v);
                    Ch[(size_t)row * N + col] = (ushort16)(u & 0xffff);
                    Cl[(size_t)row * N + col] = (ushort16)(u >> 16);
                }
            }
        }
    }
}

// ---------------- Global add pool ------------------------------------------
__device__ __forceinline__ int lower_bound_i(const int* a, int n, int key) {
    int lo = 0, hi = n;
    while (lo < hi) {
        int mid = (lo + hi) >> 1;
        if (a[mid] < key) lo = mid + 1; else hi = mid;
    }
    return lo;
}

__global__ __launch_bounds__(256) void pool_k(
    const ushort16* __restrict__ Hh, const ushort16* __restrict__ Hl,
    const int* __restrict__ batch, float* __restrict__ out)
{
    int g = blockIdx.x;
    int col = threadIdx.x;
    int lo = lower_bound_i(batch, NN, g);
    int hi = lower_bound_i(batch, NN, g + 1);
    float acc = 0.f;
    for (int n = lo; n < hi; ++n)
        acc += bf2f(Hh[(size_t)n * DD + col]) + bf2f(Hl[(size_t)n * DD + col]);
    out[(size_t)g * DD + col] = acc;
}

// ---------------------------------------------------------------------------
extern "C" void kernel_launch(void* const* d_in, const int* in_sizes, int n_in,
                              void* d_out, int out_size, void* d_ws, size_t ws_size,
                              hipStream_t stream)
{
    const int*   x        = (const int*)d_in[0];
    const int*   ei       = (const int*)d_in[1];
    const int*   ea       = (const int*)d_in[2];
    const int*   batch    = (const int*)d_in[3];
    const float* atom_emb = (const float*)d_in[4];
    const float* bond1    = (const float*)d_in[5];
    const float* bond2    = (const float*)d_in[6];
    const float* c1_w1    = (const float*)d_in[7];
    const float* c1_b1    = (const float*)d_in[8];
    const float* c1_g     = (const float*)d_in[9];
    const float* c1_be    = (const float*)d_in[10];
    const float* c1_w2    = (const float*)d_in[11];
    const float* c1_b2    = (const float*)d_in[12];
    const float* c2_w1    = (const float*)d_in[13];
    const float* c2_b1    = (const float*)d_in[14];
    const float* c2_g     = (const float*)d_in[15];
    const float* c2_be    = (const float*)d_in[16];
    const float* c2_w2    = (const float*)d_in[17];
    const float* c2_b2    = (const float*)d_in[18];
    float* out = (float*)d_out;

    // ---- workspace layout (fixed ~221 MB, same as round 6) ----
    ushort16* Hh = (ushort16*)d_ws;                    // [NN,256] bf16 hi
    ushort16* Hl = Hh + (size_t)NN * DD;               // [NN,256] bf16 lo
    ushort16* Zh = Hl + (size_t)NN * DD;               // [NN,256]
    ushort16* Zl = Zh + (size_t)NN * DD;               // [NN,256]
    float*  G    = (float*)(Zl + (size_t)NN * DD);     // [256,256]
    float*  cs   = G + 65536;                          // [256]
    float*  scl  = cs + 256;                           // [512]
    float*  shf  = scl + 512;                          // [512]
    float*  bcomb = shf + 512;                         // [1000,256]
    uint32* W1p = (uint32*)(bcomb + 1000 * DD);        // [256,512]
    uint32* W2p = W1p + 256 * 512;                     // [512,256]
    uint32* W3p = W2p + 512 * 256;                     // [256,256]
    uint32* W4p = W3p + 256 * 256;                     // [256,256]
    int* cnt    = (int*)(W4p + 256 * 256);             // [SCAN_N]
    int* rs     = cnt + SCAN_N;                        // [SCAN_N]
    int* bsum   = rs + SCAN_N;                         // [512]
    int* boff   = bsum + 512;                          // [512]
    int* cursor = boff + 512;                          // [NN]
    int* meta   = cursor + NN;                         // [NE]
    char* ybase = (char*)(meta + NE);                  // ystrip planes

    size_t fixed_bytes = (size_t)(ybase - (char*)d_ws);
    size_t avail = ws_size > fixed_bytes ? ws_size - fixed_bytes : 0;
    int strip = (int)(avail / 2048);                   // 512 cols x 2 planes x 2B
    strip = (strip / 128) * 128;
    if (strip > 50048) strip = 50048;
    if (strip < 128) strip = 128;
    ushort16* ysh = (ushort16*)ybase;
    ushort16* ysl = ysh + (size_t)strip * 512;

    const int eb = (NE + 255) / 256;

    zero_k<<<(SCAN_N + 255) / 256, 256, 0, stream>>>((float*)cnt, SCAN_N);
    zero_k<<<(65792 + 255) / 256, 256, 0, stream>>>(G, 65792);   // G + cs

    // weight packs (once per call)
    packmat_k<<<512, 256, 0, stream>>>(c1_w1, W1p, 256 * 512);
    packmat_k<<<512, 256, 0, stream>>>(c1_w2, W2p, 512 * 256);
    packmat_k<<<256, 256, 0, stream>>>(c2_w1, W3p, 256 * 256);
    packmat_k<<<256, 256, 0, stream>>>(c2_w2, W4p, 256 * 256);

    atom_embed_k<<<NN / 4, 256, 0, stream>>>(x, atom_emb, Hh, Hl);

    // CSR build (conv-invariant)
    hist_k<<<eb, 256, 0, stream>>>(ei, cnt);
    scan1_k<<<SCAN_B, 256, 0, stream>>>(cnt, bsum);
    scan2_k<<<1, 512, 0, stream>>>(bsum, boff);
    scan3_k<<<SCAN_B, 256, 0, stream>>>(cnt, boff, rs, cursor);
    scatter_k<<<eb, 256, 0, stream>>>(ei, ea, cursor, meta);

    // ================= conv1 =================
    bcomb_k<<<1000, 256, 0, stream>>>(bond1, bcomb);
    gather_full_k<<<NN / 4, 256, 0, stream>>>(Hh, Hl, bcomb, rs, meta, Zh, Zl);
    gram_mfma_k<<<4 * NGCH, 256, 0, stream>>>(Zh, Zl, G);
    colsum_k<<<SCAN_B, 256, 0, stream>>>(Zh, Zl, cs);
    bnprep_k<<<512, 256, 0, stream>>>(G, cs, c1_w1, c1_b1, c1_g, c1_be, scl, shf, 512);
    for (int r0 = 0; r0 < NN; r0 += strip) {
        int Ms = (NN - r0 < strip) ? NN - r0 : strip;
        int mt = (Ms + 127) / 128;
        gemm_mfma_k<2><<<mt * 4, 256, 0, stream>>>(
            Zh + (size_t)r0 * DD, Zl + (size_t)r0 * DD, W1p, c1_b1,
            ysh, ysl, Ms, 512, 256, scl, shf);
        gemm_mfma_k<1><<<mt * 2, 256, 0, stream>>>(
            ysh, ysl, W2p, c1_b2,
            Hh + (size_t)r0 * DD, Hl + (size_t)r0 * DD, Ms, 256, 512, nullptr, nullptr);
    }

    // ================= conv2 =================
    zero_k<<<(65792 + 255) / 256, 256, 0, stream>>>(G, 65792);
    bcomb_k<<<1000, 256, 0, stream>>>(bond2, bcomb);
    gather_full_k<<<NN / 4, 256, 0, stream>>>(Hh, Hl, bcomb, rs, meta, Zh, Zl);
    gram_mfma_k<<<4 * NGCH, 256, 0, stream>>>(Zh, Zl, G);
    colsum_k<<<SCAN_B, 256, 0, stream>>>(Zh, Zl, cs);
    bnprep_k<<<256, 256, 0, stream>>>(G, cs, c2_w1, c2_b1, c2_g, c2_be, scl, shf, 256);
    for (int r0 = 0; r0 < NN; r0 += strip) {
        int Ms = (NN - r0 < strip) ? NN - r0 : strip;
        int mt = (Ms + 127) / 128;
        gemm_mfma_k<2><<<mt * 2, 256, 0, stream>>>(
            Zh + (size_t)r0 * DD, Zl + (size_t)r0 * DD, W3p, c2_b1,
            ysh, ysl, Ms, 256, 256, scl, shf);
        gemm_mfma_k<1><<<mt * 2, 256, 0, stream>>>(
            ysh, ysl, W4p, c2_b2,
            Hh + (size_t)r0 * DD, Hl + (size_t)r0 * DD, Ms, 256, 256, nullptr, nullptr);
    }

    // ---- pool ----
    pool_k<<<NG, 256, 0, stream>>>(Hh, Hl, batch, out);
}

// Round 8
// 2263.542 us; speedup vs baseline: 1.9336x; 1.0186x over previous
//
#include <hip/hip_runtime.h>

#define NN 100000
#define NE 3200000
#define NG 2048
#define DD 256
#define EPSV 1e-5f
#define SCAN_N 100096           // 391 * 256 >= NN+1
#define SCAN_B 391
#define GCH 1568                // gram split-K chunk rows
#define NGCH 64

typedef unsigned int uint32;
typedef unsigned short ushort16;
typedef __attribute__((ext_vector_type(4))) unsigned int uivec4;
typedef __attribute__((ext_vector_type(4))) unsigned short usvec4;
typedef __attribute__((ext_vector_type(4))) float f32x4;
typedef __attribute__((ext_vector_type(8))) short short8_t;

__device__ __forceinline__ float4 ld4(const float* p) {
    return *reinterpret_cast<const float4*>(p);
}
__device__ __forceinline__ float bf2f(ushort16 b) {
    return __uint_as_float((uint32)b << 16);
}

// ---- split-bf16: hi = RNE-bf16(x), lo = bf16(x - hi); u = hi | lo<<16 ------
__device__ __forceinline__ uint32 packsplit(float x) {
    uint32 u = __float_as_uint(x);
    uint32 hb = (u + 0x7fffu + ((u >> 16) & 1u)) >> 16;   // RNE
    float hf = __uint_as_float(hb << 16);
    float lo = x - hf;
    uint32 lb = __float_as_uint(lo) >> 16;
    return hb | (lb << 16);
}

// ---------------- zero fill ------------------------------------------------
__global__ __launch_bounds__(256) void zero_k(float* __restrict__ p, int n) {
    int i = blockIdx.x * 256 + threadIdx.x;
    if (i < n) p[i] = 0.f;
}

// ---------------- pack f32 weights into combined u32 split form ------------
__global__ __launch_bounds__(256) void packmat_k(const float* __restrict__ X,
                                                 uint32* __restrict__ Xp, int n) {
    int i = blockIdx.x * 256 + threadIdx.x;
    if (i < n) Xp[i] = packsplit(X[i]);
}

// ---------------- Atom encoder (writes H planes) ---------------------------
__global__ __launch_bounds__(256) void atom_embed_k(
    const int* __restrict__ x, const float* __restrict__ emb,
    ushort16* __restrict__ Hh, ushort16* __restrict__ Hl)
{
    int lane = threadIdx.x & 63;
    int n = blockIdx.x * 4 + (threadIdx.x >> 6);
    if (n >= NN) return;
    int c4 = lane * 4;
    float4 acc = make_float4(0.f, 0.f, 0.f, 0.f);
#pragma unroll
    for (int c = 0; c < 9; ++c) {
        int idx = x[n * 9 + c];
        float4 v = ld4(emb + (size_t)(c * 100 + idx) * DD + c4);
        acc.x += v.x; acc.y += v.y; acc.z += v.z; acc.w += v.w;
    }
    float a[4] = {acc.x, acc.y, acc.z, acc.w};
    usvec4 h, l;
#pragma unroll
    for (int j = 0; j < 4; ++j) {
        uint32 u = packsplit(a[j]);
        h[j] = (ushort16)(u & 0xffff);
        l[j] = (ushort16)(u >> 16);
    }
    *reinterpret_cast<usvec4*>(Hh + (size_t)n * DD + c4) = h;
    *reinterpret_cast<usvec4*>(Hl + (size_t)n * DD + c4) = l;
}

// ---------------- bond combo table (f32) -----------------------------------
__global__ __launch_bounds__(256) void bcomb_k(const float* __restrict__ bond,
                                               float* __restrict__ bcomb)
{
    int combo = blockIdx.x;          // 0..999
    int col = threadIdx.x;
    int b0 = combo % 10, b1 = (combo / 10) % 10, b2 = combo / 100;
    bcomb[(size_t)combo * DD + col] =
        bond[(size_t)b0 * DD + col] +
        bond[(size_t)(10 + b1) * DD + col] +
        bond[(size_t)(20 + b2) * DD + col];
}

// ---------------- CSR build ------------------------------------------------
__global__ __launch_bounds__(256) void hist_k(const int* __restrict__ ei,
                                              int* __restrict__ cnt)
{
    int e = blockIdx.x * 256 + threadIdx.x;
    if (e < NE) atomicAdd(&cnt[ei[NE + e]], 1);
}

__global__ __launch_bounds__(256) void scan1_k(int* __restrict__ cnt,
                                               int* __restrict__ bsum)
{
    __shared__ int s[2][256];
    int t = threadIdx.x;
    int i = blockIdx.x * 256 + t;
    int v = cnt[i];
    s[0][t] = v;
    __syncthreads();
    int p = 0;
    for (int off = 1; off < 256; off <<= 1) {
        int xv = s[p][t];
        if (t >= off) xv += s[p][t - off];
        s[p ^ 1][t] = xv;
        p ^= 1;
        __syncthreads();
    }
    int inc = s[p][t];
    cnt[i] = inc - v;
    if (t == 255) bsum[blockIdx.x] = inc;
}

__global__ __launch_bounds__(512) void scan2_k(const int* __restrict__ bsum,
                                               int* __restrict__ boff)
{
    __shared__ int s[2][512];
    int t = threadIdx.x;
    int v = (t < SCAN_B) ? bsum[t] : 0;
    s[0][t] = v;
    __syncthreads();
    int p = 0;
    for (int off = 1; off < 512; off <<= 1) {
        int xv = s[p][t];
        if (t >= off) xv += s[p][t - off];
        s[p ^ 1][t] = xv;
        p ^= 1;
        __syncthreads();
    }
    boff[t] = s[p][t] - v;
}

__global__ __launch_bounds__(256) void scan3_k(const int* __restrict__ cnt,
                                               const int* __restrict__ boff,
                                               int* __restrict__ rs,
                                               int* __restrict__ cursor)
{
    int i = blockIdx.x * 256 + threadIdx.x;
    int v = cnt[i] + boff[blockIdx.x];
    rs[i] = v;
    if (i < NN) cursor[i] = v;
}

__global__ __launch_bounds__(256) void scatter_k(const int* __restrict__ ei,
                                                 const int* __restrict__ ea,
                                                 int* __restrict__ cursor,
                                                 int* __restrict__ meta)
{
    int e = blockIdx.x * 256 + threadIdx.x;
    if (e >= NE) return;
    int src = ei[e];
    int dst = ei[NE + e];
    int combo = ea[e * 3 + 0] + 10 * ea[e * 3 + 1] + 100 * ea[e * 3 + 2];
    int pos = atomicAdd(&cursor[dst], 1);
    meta[pos] = (src << 10) | combo;
}

// ---------------- Gather-aggregate: hi-plane source, NT streams ------------
// Streams (meta, Hl self, Z out) are NT so L3 retains the hot Hh (51 MB).
__device__ __forceinline__ void edge_acc(const ushort16* __restrict__ Hh,
                                         const float* __restrict__ bcomb,
                                         int m, int c4,
                                         float& a0, float& a1, float& a2, float& a3)
{
    usvec4 v = *reinterpret_cast<const usvec4*>(Hh + (size_t)(m >> 10) * DD + c4);
    float4 b = ld4(bcomb + (size_t)(m & 1023) * DD + c4);
    a0 += fmaxf(bf2f(v[0]) + b.x, 0.f);
    a1 += fmaxf(bf2f(v[1]) + b.y, 0.f);
    a2 += fmaxf(bf2f(v[2]) + b.z, 0.f);
    a3 += fmaxf(bf2f(v[3]) + b.w, 0.f);
}

__global__ __launch_bounds__(256) void gather_full_k(
    const ushort16* __restrict__ Hh, const ushort16* __restrict__ Hl,
    const float* __restrict__ bcomb,
    const int* __restrict__ rs, const int* __restrict__ meta,
    ushort16* __restrict__ Zh, ushort16* __restrict__ Zl)
{
    int lane = threadIdx.x & 63;
    int n = blockIdx.x * 4 + (threadIdx.x >> 6);
    if (n >= NN) return;
    int c4 = lane * 4;
    usvec4 sh = *reinterpret_cast<const usvec4*>(Hh + (size_t)n * DD + c4);
    usvec4 sl = __builtin_nontemporal_load(
        reinterpret_cast<const usvec4*>(Hl + (size_t)n * DD + c4));
    float a0 = bf2f(sh[0]) + bf2f(sl[0]);
    float a1 = bf2f(sh[1]) + bf2f(sl[1]);
    float a2 = bf2f(sh[2]) + bf2f(sl[2]);
    float a3 = bf2f(sh[3]) + bf2f(sl[3]);
    int lo = rs[n], hi = rs[n + 1];
    int t = lo;
    for (; t + 4 <= hi; t += 4) {
        int m0 = __builtin_nontemporal_load(meta + t);
        int m1 = __builtin_nontemporal_load(meta + t + 1);
        int m2 = __builtin_nontemporal_load(meta + t + 2);
        int m3 = __builtin_nontemporal_load(meta + t + 3);
        edge_acc(Hh, bcomb, m0, c4, a0, a1, a2, a3);
        edge_acc(Hh, bcomb, m1, c4, a0, a1, a2, a3);
        edge_acc(Hh, bcomb, m2, c4, a0, a1, a2, a3);
        edge_acc(Hh, bcomb, m3, c4, a0, a1, a2, a3);
    }
    for (; t < hi; ++t)
        edge_acc(Hh, bcomb, __builtin_nontemporal_load(meta + t), c4, a0, a1, a2, a3);
    float a[4] = {a0, a1, a2, a3};
    usvec4 zh, zl;
#pragma unroll
    for (int j = 0; j < 4; ++j) {
        uint32 u = packsplit(a[j]);
        zh[j] = (ushort16)(u & 0xffff);
        zl[j] = (ushort16)(u >> 16);
    }
    __builtin_nontemporal_store(zh, reinterpret_cast<usvec4*>(Zh + (size_t)n * DD + c4));
    __builtin_nontemporal_store(zl, reinterpret_cast<usvec4*>(Zl + (size_t)n * DD + c4));
}

// ---------------- MFMA Gram: G += Z^T Z (planes -> packed LDS) -------------
__global__ __launch_bounds__(256) void gram_mfma_k(
    const ushort16* __restrict__ Zh, const ushort16* __restrict__ Zl,
    float* __restrict__ G)
{
    __shared__ uint32 Ta[32][130];
    __shared__ uint32 Tb[32][130];
    const int tid = threadIdx.x;
    const int lane = tid & 63;
    const int l15 = lane & 15;
    const int l4 = lane >> 4;
    const int wave = tid >> 6;
    const int wm = wave >> 1, wn = wave & 1;
    const int bj = blockIdx.x & 1;
    const int bi = (blockIdx.x >> 1) & 1;
    const int ch = blockIdx.x >> 2;
    const int rbase = ch * GCH;

    f32x4 acc[4][4] = {};

    for (int kt = 0; kt < GCH; kt += 32) {
        __syncthreads();
#pragma unroll
        for (int i = 0; i < 4; ++i) {
            int f = i * 256 + tid;
            int row = f >> 5, g4 = f & 31;      // 4-element group
            int r = rbase + kt + row;
            uivec4 pa = {0, 0, 0, 0}, pb = {0, 0, 0, 0};
            if (r < NN) {
                const ushort16* zh = Zh + (size_t)r * DD;
                const ushort16* zl = Zl + (size_t)r * DD;
                usvec4 ah_ = *reinterpret_cast<const usvec4*>(zh + bi * 128 + g4 * 4);
                usvec4 al_ = *reinterpret_cast<const usvec4*>(zl + bi * 128 + g4 * 4);
                usvec4 bh_ = *reinterpret_cast<const usvec4*>(zh + bj * 128 + g4 * 4);
                usvec4 bl_ = *reinterpret_cast<const usvec4*>(zl + bj * 128 + g4 * 4);
#pragma unroll
                for (int j = 0; j < 4; ++j) {
                    pa[j] = (uint32)ah_[j] | ((uint32)al_[j] << 16);
                    pb[j] = (uint32)bh_[j] | ((uint32)bl_[j] << 16);
                }
            }
            *reinterpret_cast<uivec4*>(&Ta[row][g4 * 4]) = pa;
            *reinterpret_cast<uivec4*>(&Tb[row][g4 * 4]) = pb;
        }
        __syncthreads();

        short8_t ah[4], al[4], bh[4], bl[4];
#pragma unroll
        for (int mi = 0; mi < 4; ++mi) {
            int ci = wm * 64 + mi * 16 + l15;
            short8_t h, l;
#pragma unroll
            for (int j = 0; j < 8; ++j) {
                uint32 u = Ta[l4 * 8 + j][ci];
                h[j] = (short)(u & 0xffff);
                l[j] = (short)(u >> 16);
            }
            ah[mi] = h; al[mi] = l;
        }
#pragma unroll
        for (int ni = 0; ni < 4; ++ni) {
            int ci = wn * 64 + ni * 16 + l15;
            short8_t h, l;
#pragma unroll
            for (int j = 0; j < 8; ++j) {
                uint32 u = Tb[l4 * 8 + j][ci];
                h[j] = (short)(u & 0xffff);
                l[j] = (short)(u >> 16);
            }
            bh[ni] = h; bl[ni] = l;
        }
#pragma unroll
        for (int mi = 0; mi < 4; ++mi)
#pragma unroll
            for (int ni = 0; ni < 4; ++ni) {
                acc[mi][ni] = __builtin_amdgcn_mfma_f32_16x16x32_bf16(ah[mi], bh[ni], acc[mi][ni], 0, 0, 0);
                acc[mi][ni] = __builtin_amdgcn_mfma_f32_16x16x32_bf16(ah[mi], bl[ni], acc[mi][ni], 0, 0, 0);
                acc[mi][ni] = __builtin_amdgcn_mfma_f32_16x16x32_bf16(al[mi], bh[ni], acc[mi][ni], 0, 0, 0);
            }
    }

#pragma unroll
    for (int mi = 0; mi < 4; ++mi) {
#pragma unroll
        for (int ni = 0; ni < 4; ++ni) {
            int col = bj * 128 + wn * 64 + ni * 16 + l15;
#pragma unroll
            for (int r = 0; r < 4; ++r) {
                int row = bi * 128 + wm * 64 + mi * 16 + l4 * 4 + r;
                atomicAdd(&G[row * 256 + col], acc[mi][ni][r]);
            }
        }
    }
}

// ---------------- column sums ---------------------------------------------
__global__ __launch_bounds__(256) void colsum_k(const ushort16* __restrict__ Zh,
                                                const ushort16* __restrict__ Zl,
                                                float* __restrict__ cs)
{
    int t = threadIdx.x;
    int r0 = blockIdx.x * 256;
    int r1 = r0 + 256 < NN ? r0 + 256 : NN;
    float acc = 0.f;
    for (int r = r0; r < r1; ++r)
        acc += bf2f(Zh[(size_t)r * DD + t]) + bf2f(Zl[(size_t)r * DD + t]);
    atomicAdd(&cs[t], acc);
}

// ---------------- BN prep from Gram (f64 finalize) -------------------------
__global__ __launch_bounds__(256) void bnprep_k(
    const float* __restrict__ G, const float* __restrict__ cs,
    const float* __restrict__ W, const float* __restrict__ b,
    const float* __restrict__ g, const float* __restrict__ be,
    float* __restrict__ scl, float* __restrict__ shf, int N)
{
    __shared__ float wv[256];
    __shared__ double r1[256];
    __shared__ double r2[256];
    int c = blockIdx.x;
    int t = threadIdx.x;
    wv[t] = W[t * N + c];
    __syncthreads();
    double gd = 0.0;
    const float* Gr = G + t * 256;
    for (int j = 0; j < 256; ++j) gd += (double)Gr[j] * (double)wv[j];
    r1[t] = (double)wv[t] * gd;
    r2[t] = (double)cs[t] * (double)wv[t];
    __syncthreads();
    for (int off = 128; off > 0; off >>= 1) {
        if (t < off) { r1[t] += r1[t + off]; r2[t] += r2[t + off]; }
        __syncthreads();
    }
    if (t == 0) {
        double szw = r2[0];
        double s2zw = r1[0];
        double bb = (double)b[c];
        double fN = (double)NN;
        double S1 = szw + fN * bb;
        double S2 = s2zw + 2.0 * bb * szw + fN * bb * bb;
        double mu = S1 / fN;
        double var = S2 / fN - mu * mu;
        float s = g[c] * rsqrtf((float)var + EPSV);
        scl[c] = s;
        shf[c] = be[c] - (float)mu * s;
    }
}

// ---------------- split-bf16 MFMA GEMM -------------------------------------
// 128x128 tile, 4 waves (2x2 of 64x64), BK=32.
// ASPLIT: A has a lo plane (3 MFMA products); else lo==0 (2 products, exact).
// CSPLIT: write hi+lo planes; else RNE-bf16 hi only.
template <int OUTM, bool ASPLIT, bool CSPLIT>
__global__ __launch_bounds__(256) void gemm_mfma_k(
    const ushort16* __restrict__ Ah, const ushort16* __restrict__ Al,
    const uint32* __restrict__ Wp, const float* __restrict__ bias,
    ushort16* __restrict__ Ch, ushort16* __restrict__ Cl,
    int M, int N, int K,
    const float* __restrict__ scl, const float* __restrict__ shf)
{
    __shared__ uint32 As[128][36];

    const int tid = threadIdx.x;
    const int lane = tid & 63;
    const int l15 = lane & 15;
    const int l4 = lane >> 4;
    const int wave = tid >> 6;
    const int wm = wave >> 1, wn = wave & 1;
    const int ntx = N / 128;
    const int bx = blockIdx.x % ntx;
    const int by = blockIdx.x / ntx;
    const int row0 = by * 128, col0 = bx * 128;

    f32x4 acc[4][4] = {};

    for (int kt = 0; kt < K; kt += 32) {
        __syncthreads();
        // stage A tile, pack hi|lo<<16 into LDS (lo = 0 when !ASPLIT)
#pragma unroll
        for (int i = 0; i < 4; ++i) {
            int f = i * 256 + tid;
            int row = f >> 3, q = f & 7;         // 4-element group
            int r = row0 + row;
            if (r >= M) r = M - 1;
            usvec4 hh = *reinterpret_cast<const usvec4*>(Ah + (size_t)r * K + kt + q * 4);
            uivec4 pk;
            if constexpr (ASPLIT) {
                usvec4 ll = *reinterpret_cast<const usvec4*>(Al + (size_t)r * K + kt + q * 4);
#pragma unroll
                for (int j = 0; j < 4; ++j)
                    pk[j] = (uint32)hh[j] | ((uint32)ll[j] << 16);
            } else {
#pragma unroll
                for (int j = 0; j < 4; ++j)
                    pk[j] = (uint32)hh[j];
            }
            *reinterpret_cast<uivec4*>(&As[row][q * 4]) = pk;
        }
        __syncthreads();

        short8_t ah[4], al[4];
#pragma unroll
        for (int mi = 0; mi < 4; ++mi) {
            int m = wm * 64 + mi * 16 + l15;
            uivec4 u0 = *reinterpret_cast<const uivec4*>(&As[m][l4 * 8]);
            uivec4 u1 = *reinterpret_cast<const uivec4*>(&As[m][l4 * 8 + 4]);
            short8_t h, l;
#pragma unroll
            for (int j = 0; j < 4; ++j) {
                h[j] = (short)(u0[j] & 0xffff);
                h[4 + j] = (short)(u1[j] & 0xffff);
                if constexpr (ASPLIT) {
                    l[j] = (short)(u0[j] >> 16);
                    l[4 + j] = (short)(u1[j] >> 16);
                }
            }
            ah[mi] = h;
            if constexpr (ASPLIT) al[mi] = l;
        }
        short8_t bh[4], bl[4];
#pragma unroll
        for (int ni = 0; ni < 4; ++ni) {
            int col = col0 + wn * 64 + ni * 16 + l15;
            const uint32* wp = Wp + (size_t)(kt + l4 * 8) * N + col;
            short8_t h, l;
#pragma unroll
            for (int j = 0; j < 8; ++j) {
                uint32 u = wp[(size_t)j * N];
                h[j] = (short)(u & 0xffff);
                l[j] = (short)(u >> 16);
            }
            bh[ni] = h; bl[ni] = l;
        }
#pragma unroll
        for (int mi = 0; mi < 4; ++mi)
#pragma unroll
            for (int ni = 0; ni < 4; ++ni) {
                acc[mi][ni] = __builtin_amdgcn_mfma_f32_16x16x32_bf16(ah[mi], bh[ni], acc[mi][ni], 0, 0, 0);
                acc[mi][ni] = __builtin_amdgcn_mfma_f32_16x16x32_bf16(ah[mi], bl[ni], acc[mi][ni], 0, 0, 0);
                if constexpr (ASPLIT)
                    acc[mi][ni] = __builtin_amdgcn_mfma_f32_16x16x32_bf16(al[mi], bh[ni], acc[mi][ni], 0, 0, 0);
            }
    }

    // epilogue: C/D layout col=lane&15, row=(lane>>4)*4+reg
#pragma unroll
    for (int ni = 0; ni < 4; ++ni) {
        int col = col0 + wn * 64 + ni * 16 + l15;
        float bv = bias[col];
        float sc = 0.f, sh = 0.f;
        if constexpr (OUTM == 2) { sc = scl[col]; sh = shf[col]; }
#pragma unroll
        for (int mi = 0; mi < 4; ++mi) {
#pragma unroll
            for (int r = 0; r < 4; ++r) {
                int row = row0 + wm * 64 + mi * 16 + l4 * 4 + r;
                if (row < M) {
                    float v = acc[mi][ni][r] + bv;
                    if constexpr (OUTM == 2) v = fmaf(v, sc, sh);
                    v = fmaxf(v, 0.f);
                    uint32 u = packsplit(v);
                    Ch[(size_t)row * N + col] = (ushort16)(u & 0xffff);
                    if constexpr (CSPLIT)
                        Cl[(size_t)row * N + col] = (ushort16)(u >> 16);
                }
            }
        }
    }
}

// ---------------- Global add pool ------------------------------------------
__device__ __forceinline__ int lower_bound_i(const int* a, int n, int key) {
    int lo = 0, hi = n;
    while (lo < hi) {
        int mid = (lo + hi) >> 1;
        if (a[mid] < key) lo = mid + 1; else hi = mid;
    }
    return lo;
}

__global__ __launch_bounds__(256) void pool_k(
    const ushort16* __restrict__ Hh, const ushort16* __restrict__ Hl,
    const int* __restrict__ batch, float* __restrict__ out)
{
    int g = blockIdx.x;
    int col = threadIdx.x;
    int lo = lower_bound_i(batch, NN, g);
    int hi = lower_bound_i(batch, NN, g + 1);
    float acc = 0.f;
    for (int n = lo; n < hi; ++n)
        acc += bf2f(Hh[(size_t)n * DD + col]) + bf2f(Hl[(size_t)n * DD + col]);
    out[(size_t)g * DD + col] = acc;
}

// ---------------------------------------------------------------------------
extern "C" void kernel_launch(void* const* d_in, const int* in_sizes, int n_in,
                              void* d_out, int out_size, void* d_ws, size_t ws_size,
                              hipStream_t stream)
{
    const int*   x        = (const int*)d_in[0];
    const int*   ei       = (const int*)d_in[1];
    const int*   ea       = (const int*)d_in[2];
    const int*   batch    = (const int*)d_in[3];
    const float* atom_emb = (const float*)d_in[4];
    const float* bond1    = (const float*)d_in[5];
    const float* bond2    = (const float*)d_in[6];
    const float* c1_w1    = (const float*)d_in[7];
    const float* c1_b1    = (const float*)d_in[8];
    const float* c1_g     = (const float*)d_in[9];
    const float* c1_be    = (const float*)d_in[10];
    const float* c1_w2    = (const float*)d_in[11];
    const float* c1_b2    = (const float*)d_in[12];
    const float* c2_w1    = (const float*)d_in[13];
    const float* c2_b1    = (const float*)d_in[14];
    const float* c2_g     = (const float*)d_in[15];
    const float* c2_be    = (const float*)d_in[16];
    const float* c2_w2    = (const float*)d_in[17];
    const float* c2_b2    = (const float*)d_in[18];
    float* out = (float*)d_out;

    // ---- workspace layout ----
    ushort16* Hh = (ushort16*)d_ws;                    // [NN,256] bf16 hi
    ushort16* Hl = Hh + (size_t)NN * DD;               // [NN,256] bf16 lo
    ushort16* Zh = Hl + (size_t)NN * DD;               // [NN,256]
    ushort16* Zl = Zh + (size_t)NN * DD;               // [NN,256]
    float*  G    = (float*)(Zl + (size_t)NN * DD);     // [256,256]
    float*  cs   = G + 65536;                          // [256]
    float*  scl  = cs + 256;                           // [512]
    float*  shf  = scl + 512;                          // [512]
    float*  bcomb = shf + 512;                         // [1000,256]
    uint32* W1p = (uint32*)(bcomb + 1000 * DD);        // [256,512]
    uint32* W2p = W1p + 256 * 512;                     // [512,256]
    uint32* W3p = W2p + 512 * 256;                     // [256,256]
    uint32* W4p = W3p + 256 * 256;                     // [256,256]
    int* cnt    = (int*)(W4p + 256 * 256);             // [SCAN_N]
    int* rs     = cnt + SCAN_N;                        // [SCAN_N]
    int* bsum   = rs + SCAN_N;                         // [512]
    int* boff   = bsum + 512;                          // [512]
    int* cursor = boff + 512;                          // [NN]
    int* meta   = cursor + NN;                         // [NE]
    char* ybase = (char*)(meta + NE);                  // ystrip (single plane)

    size_t fixed_bytes = (size_t)(ybase - (char*)d_ws);
    size_t avail = ws_size > fixed_bytes ? ws_size - fixed_bytes : 0;
    int strip = (int)(avail / 1024);                   // 512 cols x 2B (hi only)
    strip = (strip / 128) * 128;
    if (strip > 100096) strip = 100096;
    if (strip < 128) strip = 128;
    ushort16* ysh = (ushort16*)ybase;

    const int eb = (NE + 255) / 256;

    zero_k<<<(SCAN_N + 255) / 256, 256, 0, stream>>>((float*)cnt, SCAN_N);
    zero_k<<<(65792 + 255) / 256, 256, 0, stream>>>(G, 65792);   // G + cs

    // weight packs (once per call)
    packmat_k<<<512, 256, 0, stream>>>(c1_w1, W1p, 256 * 512);
    packmat_k<<<512, 256, 0, stream>>>(c1_w2, W2p, 512 * 256);
    packmat_k<<<256, 256, 0, stream>>>(c2_w1, W3p, 256 * 256);
    packmat_k<<<256, 256, 0, stream>>>(c2_w2, W4p, 256 * 256);

    atom_embed_k<<<NN / 4, 256, 0, stream>>>(x, atom_emb, Hh, Hl);

    // CSR build (conv-invariant)
    hist_k<<<eb, 256, 0, stream>>>(ei, cnt);
    scan1_k<<<SCAN_B, 256, 0, stream>>>(cnt, bsum);
    scan2_k<<<1, 512, 0, stream>>>(bsum, boff);
    scan3_k<<<SCAN_B, 256, 0, stream>>>(cnt, boff, rs, cursor);
    scatter_k<<<eb, 256, 0, stream>>>(ei, ea, cursor, meta);

    // ================= conv1 =================
    bcomb_k<<<1000, 256, 0, stream>>>(bond1, bcomb);
    gather_full_k<<<NN / 4, 256, 0, stream>>>(Hh, Hl, bcomb, rs, meta, Zh, Zl);
    gram_mfma_k<<<4 * NGCH, 256, 0, stream>>>(Zh, Zl, G);
    colsum_k<<<SCAN_B, 256, 0, stream>>>(Zh, Zl, cs);
    bnprep_k<<<512, 256, 0, stream>>>(G, cs, c1_w1, c1_b1, c1_g, c1_be, scl, shf, 512);
    for (int r0 = 0; r0 < NN; r0 += strip) {
        int Ms = (NN - r0 < strip) ? NN - r0 : strip;
        int mt = (Ms + 127) / 128;
        gemm_mfma_k<2, true, false><<<mt * 4, 256, 0, stream>>>(
            Zh + (size_t)r0 * DD, Zl + (size_t)r0 * DD, W1p, c1_b1,
            ysh, nullptr, Ms, 512, 256, scl, shf);
        gemm_mfma_k<1, false, true><<<mt * 2, 256, 0, stream>>>(
            ysh, nullptr, W2p, c1_b2,
            Hh + (size_t)r0 * DD, Hl + (size_t)r0 * DD, Ms, 256, 512, nullptr, nullptr);
    }

    // ================= conv2 =================
    zero_k<<<(65792 + 255) / 256, 256, 0, stream>>>(G, 65792);
    bcomb_k<<<1000, 256, 0, stream>>>(bond2, bcomb);
    gather_full_k<<<NN / 4, 256, 0, stream>>>(Hh, Hl, bcomb, rs, meta, Zh, Zl);
    gram_mfma_k<<<4 * NGCH, 256, 0, stream>>>(Zh, Zl, G);
    colsum_k<<<SCAN_B, 256, 0, stream>>>(Zh, Zl, cs);
    bnprep_k<<<256, 256, 0, stream>>>(G, cs, c2_w1, c2_b1, c2_g, c2_be, scl, shf, 256);
    for (int r0 = 0; r0 < NN; r0 += strip) {
        int Ms = (NN - r0 < strip) ? NN - r0 : strip;
        int mt = (Ms + 127) / 128;
        gemm_mfma_k<2, true, false><<<mt * 2, 256, 0, stream>>>(
            Zh + (size_t)r0 * DD, Zl + (size_t)r0 * DD, W3p, c2_b1,
            ysh, nullptr, Ms, 256, 256, scl, shf);
        gemm_mfma_k<1, false, true><<<mt * 2, 256, 0, stream>>>(
            ysh, nullptr, W4p, c2_b2,
            Hh + (size_t)r0 * DD, Hl + (size_t)r0 * DD, Ms, 256, 256, nullptr, nullptr);
    }

    // ---- pool ----
    pool_k<<<NG, 256, 0, stream>>>(Hh, Hl, batch, out);
}

// Round 9
// 2199.720 us; speedup vs baseline: 1.9897x; 1.0290x over previous
//
#include <hip/hip_runtime.h>

#define NN 100000
#define NE 3200000
#define NG 2048
#define DD 256
#define EPSV 1e-5f
#define SCAN_N 100096           // 391 * 256 >= NN+1
#define SCAN_B 391
#define GCH 1568                // gram split-K chunk rows
#define NGCH 64

typedef unsigned int uint32;
typedef unsigned short ushort16;
typedef __attribute__((ext_vector_type(4))) unsigned int uivec4;
typedef __attribute__((ext_vector_type(2))) unsigned short usvec2;
typedef __attribute__((ext_vector_type(4))) unsigned short usvec4;
typedef __attribute__((ext_vector_type(4))) float f32x4;
typedef __attribute__((ext_vector_type(8))) short short8_t;

__device__ __forceinline__ float4 ld4(const float* p) {
    return *reinterpret_cast<const float4*>(p);
}
__device__ __forceinline__ float bf2f(ushort16 b) {
    return __uint_as_float((uint32)b << 16);
}

// ---- split-bf16: hi = RNE-bf16(x), lo = bf16(x - hi); u = hi | lo<<16 ------
__device__ __forceinline__ uint32 packsplit(float x) {
    uint32 u = __float_as_uint(x);
    uint32 hb = (u + 0x7fffu + ((u >> 16) & 1u)) >> 16;   // RNE
    float hf = __uint_as_float(hb << 16);
    float lo = x - hf;
    uint32 lb = __float_as_uint(lo) >> 16;
    return hb | (lb << 16);
}

// ---------------- zero fill ------------------------------------------------
__global__ __launch_bounds__(256) void zero_k(float* __restrict__ p, int n) {
    int i = blockIdx.x * 256 + threadIdx.x;
    if (i < n) p[i] = 0.f;
}

// ---------------- pack f32 weights into combined u32 split form ------------
__global__ __launch_bounds__(256) void packmat_k(const float* __restrict__ X,
                                                 uint32* __restrict__ Xp, int n) {
    int i = blockIdx.x * 256 + threadIdx.x;
    if (i < n) Xp[i] = packsplit(X[i]);
}

// ---------------- Atom encoder (writes H planes) ---------------------------
__global__ __launch_bounds__(256) void atom_embed_k(
    const int* __restrict__ x, const float* __restrict__ emb,
    ushort16* __restrict__ Hh, ushort16* __restrict__ Hl)
{
    int lane = threadIdx.x & 63;
    int n = blockIdx.x * 4 + (threadIdx.x >> 6);
    if (n >= NN) return;
    int c4 = lane * 4;
    float4 acc = make_float4(0.f, 0.f, 0.f, 0.f);
#pragma unroll
    for (int c = 0; c < 9; ++c) {
        int idx = x[n * 9 + c];
        float4 v = ld4(emb + (size_t)(c * 100 + idx) * DD + c4);
        acc.x += v.x; acc.y += v.y; acc.z += v.z; acc.w += v.w;
    }
    float a[4] = {acc.x, acc.y, acc.z, acc.w};
    usvec4 h, l;
#pragma unroll
    for (int j = 0; j < 4; ++j) {
        uint32 u = packsplit(a[j]);
        h[j] = (ushort16)(u & 0xffff);
        l[j] = (ushort16)(u >> 16);
    }
    *reinterpret_cast<usvec4*>(Hh + (size_t)n * DD + c4) = h;
    *reinterpret_cast<usvec4*>(Hl + (size_t)n * DD + c4) = l;
}

// ---------------- bond combo table (f32) -----------------------------------
__global__ __launch_bounds__(256) void bcomb_k(const float* __restrict__ bond,
                                               float* __restrict__ bcomb)
{
    int combo = blockIdx.x;          // 0..999
    int col = threadIdx.x;
    int b0 = combo % 10, b1 = (combo / 10) % 10, b2 = combo / 100;
    bcomb[(size_t)combo * DD + col] =
        bond[(size_t)b0 * DD + col] +
        bond[(size_t)(10 + b1) * DD + col] +
        bond[(size_t)(20 + b2) * DD + col];
}

// ---------------- CSR build ------------------------------------------------
__global__ __launch_bounds__(256) void hist_k(const int* __restrict__ ei,
                                              int* __restrict__ cnt)
{
    int e = blockIdx.x * 256 + threadIdx.x;
    if (e < NE) atomicAdd(&cnt[ei[NE + e]], 1);
}

__global__ __launch_bounds__(256) void scan1_k(int* __restrict__ cnt,
                                               int* __restrict__ bsum)
{
    __shared__ int s[2][256];
    int t = threadIdx.x;
    int i = blockIdx.x * 256 + t;
    int v = cnt[i];
    s[0][t] = v;
    __syncthreads();
    int p = 0;
    for (int off = 1; off < 256; off <<= 1) {
        int xv = s[p][t];
        if (t >= off) xv += s[p][t - off];
        s[p ^ 1][t] = xv;
        p ^= 1;
        __syncthreads();
    }
    int inc = s[p][t];
    cnt[i] = inc - v;
    if (t == 255) bsum[blockIdx.x] = inc;
}

__global__ __launch_bounds__(512) void scan2_k(const int* __restrict__ bsum,
                                               int* __restrict__ boff)
{
    __shared__ int s[2][512];
    int t = threadIdx.x;
    int v = (t < SCAN_B) ? bsum[t] : 0;
    s[0][t] = v;
    __syncthreads();
    int p = 0;
    for (int off = 1; off < 512; off <<= 1) {
        int xv = s[p][t];
        if (t >= off) xv += s[p][t - off];
        s[p ^ 1][t] = xv;
        p ^= 1;
        __syncthreads();
    }
    boff[t] = s[p][t] - v;
}

__global__ __launch_bounds__(256) void scan3_k(const int* __restrict__ cnt,
                                               const int* __restrict__ boff,
                                               int* __restrict__ rs,
                                               int* __restrict__ cursor)
{
    int i = blockIdx.x * 256 + threadIdx.x;
    int v = cnt[i] + boff[blockIdx.x];
    rs[i] = v;
    if (i < NN) cursor[i] = v;
}

__global__ __launch_bounds__(256) void scatter_k(const int* __restrict__ ei,
                                                 const int* __restrict__ ea,
                                                 int* __restrict__ cursor,
                                                 int* __restrict__ meta)
{
    int e = blockIdx.x * 256 + threadIdx.x;
    if (e >= NE) return;
    int src = ei[e];
    int dst = ei[NE + e];
    int combo = ea[e * 3 + 0] + 10 * ea[e * 3 + 1] + 100 * ea[e * 3 + 2];
    int pos = atomicAdd(&cursor[dst], 1);
    meta[pos] = (src << 10) | combo;
}

// ---------------- Gather-aggregate (round-7 proven form, no NT) ------------
__device__ __forceinline__ void edge_acc(const ushort16* __restrict__ Hh,
                                         const float* __restrict__ bcomb,
                                         int m, int c4,
                                         float& a0, float& a1, float& a2, float& a3)
{
    usvec4 v = *reinterpret_cast<const usvec4*>(Hh + (size_t)(m >> 10) * DD + c4);
    float4 b = ld4(bcomb + (size_t)(m & 1023) * DD + c4);
    a0 += fmaxf(bf2f(v[0]) + b.x, 0.f);
    a1 += fmaxf(bf2f(v[1]) + b.y, 0.f);
    a2 += fmaxf(bf2f(v[2]) + b.z, 0.f);
    a3 += fmaxf(bf2f(v[3]) + b.w, 0.f);
}

__global__ __launch_bounds__(256) void gather_full_k(
    const ushort16* __restrict__ Hh, const ushort16* __restrict__ Hl,
    const float* __restrict__ bcomb,
    const int* __restrict__ rs, const int* __restrict__ meta,
    ushort16* __restrict__ Zh, ushort16* __restrict__ Zl)
{
    int lane = threadIdx.x & 63;
    int n = blockIdx.x * 4 + (threadIdx.x >> 6);
    if (n >= NN) return;
    int c4 = lane * 4;
    usvec4 sh = *reinterpret_cast<const usvec4*>(Hh + (size_t)n * DD + c4);
    usvec4 sl = *reinterpret_cast<const usvec4*>(Hl + (size_t)n * DD + c4);
    float a0 = bf2f(sh[0]) + bf2f(sl[0]);
    float a1 = bf2f(sh[1]) + bf2f(sl[1]);
    float a2 = bf2f(sh[2]) + bf2f(sl[2]);
    float a3 = bf2f(sh[3]) + bf2f(sl[3]);
    int lo = rs[n], hi = rs[n + 1];
    int t = lo;
    for (; t + 4 <= hi; t += 4) {
        int m0 = meta[t], m1 = meta[t + 1], m2 = meta[t + 2], m3 = meta[t + 3];
        edge_acc(Hh, bcomb, m0, c4, a0, a1, a2, a3);
        edge_acc(Hh, bcomb, m1, c4, a0, a1, a2, a3);
        edge_acc(Hh, bcomb, m2, c4, a0, a1, a2, a3);
        edge_acc(Hh, bcomb, m3, c4, a0, a1, a2, a3);
    }
    for (; t < hi; ++t)
        edge_acc(Hh, bcomb, meta[t], c4, a0, a1, a2, a3);
    float a[4] = {a0, a1, a2, a3};
    usvec4 zh, zl;
#pragma unroll
    for (int j = 0; j < 4; ++j) {
        uint32 u = packsplit(a[j]);
        zh[j] = (ushort16)(u & 0xffff);
        zl[j] = (ushort16)(u >> 16);
    }
    *reinterpret_cast<usvec4*>(Zh + (size_t)n * DD + c4) = zh;
    *reinterpret_cast<usvec4*>(Zl + (size_t)n * DD + c4) = zl;
}

// ---------------- MFMA Gram: G += Z^T Z ------------------------------------
// Col-major LDS [col][36] (16B-aligned pitch, conflict-free b128 frag reads),
// software-pipelined global->reg->LDS staging.
__global__ __launch_bounds__(256) void gram_mfma_k(
    const ushort16* __restrict__ Zh, const ushort16* __restrict__ Zl,
    float* __restrict__ G)
{
    __shared__ uint32 Ta[128][36];
    __shared__ uint32 Tb[128][36];
    const int tid = threadIdx.x;
    const int lane = tid & 63;
    const int l15 = lane & 15;
    const int l4 = lane >> 4;
    const int wave = tid >> 6;
    const int wm = wave >> 1, wn = wave & 1;
    const int bj = blockIdx.x & 1;
    const int bi = (blockIdx.x >> 1) & 1;
    const int ch = blockIdx.x >> 2;
    const int rbase = ch * GCH;

    const int cp = tid & 63;          // col pair: cols 2cp, 2cp+1
    const int col2 = cp * 2;

    f32x4 acc[4][4] = {};
    uivec4 rA0[2], rA1[2], rB0[2], rB1[2];   // [iter][which col of pair]

    auto LOADG = [&](int kt) {
#pragma unroll
        for (int i = 0; i < 2; ++i) {
            int kg = i * 4 + (tid >> 6);
            uivec4 pa0, pa1, pb0, pb1;
#pragma unroll
            for (int jj = 0; jj < 4; ++jj) {
                int r = rbase + kt + kg * 4 + jj;
                uint32 va0 = 0, va1 = 0, vb0 = 0, vb1 = 0;
                if (r < NN) {
                    size_t ro = (size_t)r * DD;
                    usvec2 ah_ = *reinterpret_cast<const usvec2*>(Zh + ro + bi * 128 + col2);
                    usvec2 al_ = *reinterpret_cast<const usvec2*>(Zl + ro + bi * 128 + col2);
                    usvec2 bh_ = *reinterpret_cast<const usvec2*>(Zh + ro + bj * 128 + col2);
                    usvec2 bl_ = *reinterpret_cast<const usvec2*>(Zl + ro + bj * 128 + col2);
                    va0 = (uint32)ah_[0] | ((uint32)al_[0] << 16);
                    va1 = (uint32)ah_[1] | ((uint32)al_[1] << 16);
                    vb0 = (uint32)bh_[0] | ((uint32)bl_[0] << 16);
                    vb1 = (uint32)bh_[1] | ((uint32)bl_[1] << 16);
                }
                pa0[jj] = va0; pa1[jj] = va1; pb0[jj] = vb0; pb1[jj] = vb1;
            }
            rA0[i] = pa0; rA1[i] = pa1; rB0[i] = pb0; rB1[i] = pb1;
        }
    };

    LOADG(0);
    for (int kt = 0; kt < GCH; kt += 32) {
#pragma unroll
        for (int i = 0; i < 2; ++i) {
            int kg = i * 4 + (tid >> 6);
            *reinterpret_cast<uivec4*>(&Ta[col2][kg * 4])     = rA0[i];
            *reinterpret_cast<uivec4*>(&Ta[col2 + 1][kg * 4]) = rA1[i];
            *reinterpret_cast<uivec4*>(&Tb[col2][kg * 4])     = rB0[i];
            *reinterpret_cast<uivec4*>(&Tb[col2 + 1][kg * 4]) = rB1[i];
        }
        __syncthreads();
        if (kt + 32 < GCH) LOADG(kt + 32);

        short8_t ah[4], al[4], bh[4], bl[4];
#pragma unroll
        for (int mi = 0; mi < 4; ++mi) {
            int ci = wm * 64 + mi * 16 + l15;
            uivec4 u0 = *reinterpret_cast<const uivec4*>(&Ta[ci][l4 * 8]);
            uivec4 u1 = *reinterpret_cast<const uivec4*>(&Ta[ci][l4 * 8 + 4]);
            short8_t h, l;
#pragma unroll
            for (int j = 0; j < 4; ++j) {
                h[j] = (short)(u0[j] & 0xffff);     l[j] = (short)(u0[j] >> 16);
                h[4 + j] = (short)(u1[j] & 0xffff); l[4 + j] = (short)(u1[j] >> 16);
            }
            ah[mi] = h; al[mi] = l;
        }
#pragma unroll
        for (int ni = 0; ni < 4; ++ni) {
            int ci = wn * 64 + ni * 16 + l15;
            uivec4 u0 = *reinterpret_cast<const uivec4*>(&Tb[ci][l4 * 8]);
            uivec4 u1 = *reinterpret_cast<const uivec4*>(&Tb[ci][l4 * 8 + 4]);
            short8_t h, l;
#pragma unroll
            for (int j = 0; j < 4; ++j) {
                h[j] = (short)(u0[j] & 0xffff);     l[j] = (short)(u0[j] >> 16);
                h[4 + j] = (short)(u1[j] & 0xffff); l[4 + j] = (short)(u1[j] >> 16);
            }
            bh[ni] = h; bl[ni] = l;
        }
#pragma unroll
        for (int mi = 0; mi < 4; ++mi)
#pragma unroll
            for (int ni = 0; ni < 4; ++ni) {
                acc[mi][ni] = __builtin_amdgcn_mfma_f32_16x16x32_bf16(ah[mi], bh[ni], acc[mi][ni], 0, 0, 0);
                acc[mi][ni] = __builtin_amdgcn_mfma_f32_16x16x32_bf16(ah[mi], bl[ni], acc[mi][ni], 0, 0, 0);
                acc[mi][ni] = __builtin_amdgcn_mfma_f32_16x16x32_bf16(al[mi], bh[ni], acc[mi][ni], 0, 0, 0);
            }
        __syncthreads();
    }

#pragma unroll
    for (int mi = 0; mi < 4; ++mi) {
#pragma unroll
        for (int ni = 0; ni < 4; ++ni) {
            int col = bj * 128 + wn * 64 + ni * 16 + l15;
#pragma unroll
            for (int r = 0; r < 4; ++r) {
                int row = bi * 128 + wm * 64 + mi * 16 + l4 * 4 + r;
                atomicAdd(&G[row * 256 + col], acc[mi][ni][r]);
            }
        }
    }
}

// ---------------- column sums ---------------------------------------------
__global__ __launch_bounds__(256) void colsum_k(const ushort16* __restrict__ Zh,
                                                const ushort16* __restrict__ Zl,
                                                float* __restrict__ cs)
{
    int t = threadIdx.x;
    int r0 = blockIdx.x * 256;
    int r1 = r0 + 256 < NN ? r0 + 256 : NN;
    float acc = 0.f;
    for (int r = r0; r < r1; ++r)
        acc += bf2f(Zh[(size_t)r * DD + t]) + bf2f(Zl[(size_t)r * DD + t]);
    atomicAdd(&cs[t], acc);
}

// ---------------- BN prep from Gram (f64 finalize) -------------------------
__global__ __launch_bounds__(256) void bnprep_k(
    const float* __restrict__ G, const float* __restrict__ cs,
    const float* __restrict__ W, const float* __restrict__ b,
    const float* __restrict__ g, const float* __restrict__ be,
    float* __restrict__ scl, float* __restrict__ shf, int N)
{
    __shared__ float wv[256];
    __shared__ double r1[256];
    __shared__ double r2[256];
    int c = blockIdx.x;
    int t = threadIdx.x;
    wv[t] = W[t * N + c];
    __syncthreads();
    double gd = 0.0;
    const float* Gr = G + t * 256;
    for (int j = 0; j < 256; ++j) gd += (double)Gr[j] * (double)wv[j];
    r1[t] = (double)wv[t] * gd;
    r2[t] = (double)cs[t] * (double)wv[t];
    __syncthreads();
    for (int off = 128; off > 0; off >>= 1) {
        if (t < off) { r1[t] += r1[t + off]; r2[t] += r2[t + off]; }
        __syncthreads();
    }
    if (t == 0) {
        double szw = r2[0];
        double s2zw = r1[0];
        double bb = (double)b[c];
        double fN = (double)NN;
        double S1 = szw + fN * bb;
        double S2 = s2zw + 2.0 * bb * szw + fN * bb * bb;
        double mu = S1 / fN;
        double var = S2 / fN - mu * mu;
        float s = g[c] * rsqrtf((float)var + EPSV);
        scl[c] = s;
        shf[c] = be[c] - (float)mu * s;
    }
}

// ---------------- split-bf16 MFMA GEMM -------------------------------------
// 128x128 tile, 4 waves, BK=32. B staged in col-major LDS [col][36] shared by
// all waves (conflict-free b128); global->reg->LDS pipeline hides latency.
// ASPLIT: A has lo plane (3 products); else 2 products (exact, lo==0).
// CSPLIT: write hi+lo planes; else RNE-bf16 hi only.
template <int OUTM, bool ASPLIT, bool CSPLIT>
__global__ __launch_bounds__(256) void gemm_mfma_k(
    const ushort16* __restrict__ Ah, const ushort16* __restrict__ Al,
    const uint32* __restrict__ Wp, const float* __restrict__ bias,
    ushort16* __restrict__ Ch, ushort16* __restrict__ Cl,
    int M, int N, int K,
    const float* __restrict__ scl, const float* __restrict__ shf)
{
    __shared__ uint32 As[128][36];    // [row][k]
    __shared__ uint32 Bs[128][36];    // [col][k]

    const int tid = threadIdx.x;
    const int lane = tid & 63;
    const int l15 = lane & 15;
    const int l4 = lane >> 4;
    const int wave = tid >> 6;
    const int wm = wave >> 1, wn = wave & 1;
    const int ntx = N / 128;
    const int bx = blockIdx.x % ntx;
    const int by = blockIdx.x / ntx;
    const int row0 = by * 128, col0 = bx * 128;

    f32x4 acc[4][4] = {};
    uivec4 rA[4], rB[4];

    auto LOADA = [&](int kt) {
#pragma unroll
        for (int i = 0; i < 4; ++i) {
            int f = i * 256 + tid;
            int row = f >> 3, q = f & 7;
            int r = row0 + row;
            if (r >= M) r = M - 1;
            usvec4 hh = *reinterpret_cast<const usvec4*>(Ah + (size_t)r * K + kt + q * 4);
            uivec4 pk;
            if constexpr (ASPLIT) {
                usvec4 ll = *reinterpret_cast<const usvec4*>(Al + (size_t)r * K + kt + q * 4);
#pragma unroll
                for (int j = 0; j < 4; ++j)
                    pk[j] = (uint32)hh[j] | ((uint32)ll[j] << 16);
            } else {
#pragma unroll
                for (int j = 0; j < 4; ++j)
                    pk[j] = (uint32)hh[j];
            }
            rA[i] = pk;
        }
    };
    auto LOADB = [&](int kt) {
#pragma unroll
        for (int i = 0; i < 4; ++i) {
            int f = i * 256 + tid;
            int col = f & 127, kg = f >> 7;
            const uint32* wp = Wp + (size_t)(kt + kg * 4) * N + col0 + col;
            uivec4 w;
#pragma unroll
            for (int jj = 0; jj < 4; ++jj) w[jj] = wp[(size_t)jj * N];
            rB[i] = w;
        }
    };

    LOADA(0); LOADB(0);
    for (int kt = 0; kt < K; kt += 32) {
#pragma unroll
        for (int i = 0; i < 4; ++i) {
            int f = i * 256 + tid;
            int row = f >> 3, q = f & 7;
            *reinterpret_cast<uivec4*>(&As[row][q * 4]) = rA[i];
            int col = f & 127, kg = f >> 7;
            *reinterpret_cast<uivec4*>(&Bs[col][kg * 4]) = rB[i];
        }
        __syncthreads();
        if (kt + 32 < K) { LOADA(kt + 32); LOADB(kt + 32); }

        short8_t ah[4], al[4];
#pragma unroll
        for (int mi = 0; mi < 4; ++mi) {
            int m = wm * 64 + mi * 16 + l15;
            uivec4 u0 = *reinterpret_cast<const uivec4*>(&As[m][l4 * 8]);
            uivec4 u1 = *reinterpret_cast<const uivec4*>(&As[m][l4 * 8 + 4]);
            short8_t h, l;
#pragma unroll
            for (int j = 0; j < 4; ++j) {
                h[j] = (short)(u0[j] & 0xffff);
                h[4 + j] = (short)(u1[j] & 0xffff);
                if constexpr (ASPLIT) {
                    l[j] = (short)(u0[j] >> 16);
                    l[4 + j] = (short)(u1[j] >> 16);
                }
            }
            ah[mi] = h;
            if constexpr (ASPLIT) al[mi] = l;
        }
        short8_t bh[4], bl[4];
#pragma unroll
        for (int ni = 0; ni < 4; ++ni) {
            int ci = wn * 64 + ni * 16 + l15;
            uivec4 u0 = *reinterpret_cast<const uivec4*>(&Bs[ci][l4 * 8]);
            uivec4 u1 = *reinterpret_cast<const uivec4*>(&Bs[ci][l4 * 8 + 4]);
            short8_t h, l;
#pragma unroll
            for (int j = 0; j < 4; ++j) {
                h[j] = (short)(u0[j] & 0xffff);     l[j] = (short)(u0[j] >> 16);
                h[4 + j] = (short)(u1[j] & 0xffff); l[4 + j] = (short)(u1[j] >> 16);
            }
            bh[ni] = h; bl[ni] = l;
        }
#pragma unroll
        for (int mi = 0; mi < 4; ++mi)
#pragma unroll
            for (int ni = 0; ni < 4; ++ni) {
                acc[mi][ni] = __builtin_amdgcn_mfma_f32_16x16x32_bf16(ah[mi], bh[ni], acc[mi][ni], 0, 0, 0);
                acc[mi][ni] = __builtin_amdgcn_mfma_f32_16x16x32_bf16(ah[mi], bl[ni], acc[mi][ni], 0, 0, 0);
                if constexpr (ASPLIT)
                    acc[mi][ni] = __builtin_amdgcn_mfma_f32_16x16x32_bf16(al[mi], bh[ni], acc[mi][ni], 0, 0, 0);
            }
        __syncthreads();
    }

    // epilogue: C/D layout col=lane&15, row=(lane>>4)*4+reg
#pragma unroll
    for (int ni = 0; ni < 4; ++ni) {
        int col = col0 + wn * 64 + ni * 16 + l15;
        float bv = bias[col];
        float sc = 0.f, sh = 0.f;
        if constexpr (OUTM == 2) { sc = scl[col]; sh = shf[col]; }
#pragma unroll
        for (int mi = 0; mi < 4; ++mi) {
#pragma unroll
            for (int r = 0; r < 4; ++r) {
                int row = row0 + wm * 64 + mi * 16 + l4 * 4 + r;
                if (row < M) {
                    float v = acc[mi][ni][r] + bv;
                    if constexpr (OUTM == 2) v = fmaf(v, sc, sh);
                    v = fmaxf(v, 0.f);
                    uint32 u = packsplit(v);
                    Ch[(size_t)row * N + col] = (ushort16)(u & 0xffff);
                    if constexpr (CSPLIT)
                        Cl[(size_t)row * N + col] = (ushort16)(u >> 16);
                }
            }
        }
    }
}

// ---------------- Global add pool ------------------------------------------
__device__ __forceinline__ int lower_bound_i(const int* a, int n, int key) {
    int lo = 0, hi = n;
    while (lo < hi) {
        int mid = (lo + hi) >> 1;
        if (a[mid] < key) lo = mid + 1; else hi = mid;
    }
    return lo;
}

__global__ __launch_bounds__(256) void pool_k(
    const ushort16* __restrict__ Hh, const ushort16* __restrict__ Hl,
    const int* __restrict__ batch, float* __restrict__ out)
{
    int g = blockIdx.x;
    int col = threadIdx.x;
    int lo = lower_bound_i(batch, NN, g);
    int hi = lower_bound_i(batch, NN, g + 1);
    float acc = 0.f;
    for (int n = lo; n < hi; ++n)
        acc += bf2f(Hh[(size_t)n * DD + col]) + bf2f(Hl[(size_t)n * DD + col]);
    out[(size_t)g * DD + col] = acc;
}

// ---------------------------------------------------------------------------
extern "C" void kernel_launch(void* const* d_in, const int* in_sizes, int n_in,
                              void* d_out, int out_size, void* d_ws, size_t ws_size,
                              hipStream_t stream)
{
    const int*   x        = (const int*)d_in[0];
    const int*   ei       = (const int*)d_in[1];
    const int*   ea       = (const int*)d_in[2];
    const int*   batch    = (const int*)d_in[3];
    const float* atom_emb = (const float*)d_in[4];
    const float* bond1    = (const float*)d_in[5];
    const float* bond2    = (const float*)d_in[6];
    const float* c1_w1    = (const float*)d_in[7];
    const float* c1_b1    = (const float*)d_in[8];
    const float* c1_g     = (const float*)d_in[9];
    const float* c1_be    = (const float*)d_in[10];
    const float* c1_w2    = (const float*)d_in[11];
    const float* c1_b2    = (const float*)d_in[12];
    const float* c2_w1    = (const float*)d_in[13];
    const float* c2_b1    = (const float*)d_in[14];
    const float* c2_g     = (const float*)d_in[15];
    const float* c2_be    = (const float*)d_in[16];
    const float* c2_w2    = (const float*)d_in[17];
    const float* c2_b2    = (const float*)d_in[18];
    float* out = (float*)d_out;

    // ---- workspace layout ----
    ushort16* Hh = (ushort16*)d_ws;                    // [NN,256] bf16 hi
    ushort16* Hl = Hh + (size_t)NN * DD;               // [NN,256] bf16 lo
    ushort16* Zh = Hl + (size_t)NN * DD;               // [NN,256]
    ushort16* Zl = Zh + (size_t)NN * DD;               // [NN,256]
    float*  G    = (float*)(Zl + (size_t)NN * DD);     // [256,256]
    float*  cs   = G + 65536;                          // [256]
    float*  scl  = cs + 256;                           // [512]
    float*  shf  = scl + 512;                          // [512]
    float*  bcomb = shf + 512;                         // [1000,256]
    uint32* W1p = (uint32*)(bcomb + 1000 * DD);        // [256,512]
    uint32* W2p = W1p + 256 * 512;                     // [512,256]
    uint32* W3p = W2p + 512 * 256;                     // [256,256]
    uint32* W4p = W3p + 256 * 256;                     // [256,256]
    int* cnt    = (int*)(W4p + 256 * 256);             // [SCAN_N]
    int* rs     = cnt + SCAN_N;                        // [SCAN_N]
    int* bsum   = rs + SCAN_N;                         // [512]
    int* boff   = bsum + 512;                          // [512]
    int* cursor = boff + 512;                          // [NN]
    int* meta   = cursor + NN;                         // [NE]
    char* ybase = (char*)(meta + NE);                  // ystrip (single plane)

    size_t fixed_bytes = (size_t)(ybase - (char*)d_ws);
    size_t avail = ws_size > fixed_bytes ? ws_size - fixed_bytes : 0;
    int strip = (int)(avail / 1024);                   // 512 cols x 2B (hi only)
    strip = (strip / 128) * 128;
    if (strip > 100096) strip = 100096;
    if (strip < 128) strip = 128;
    ushort16* ysh = (ushort16*)ybase;

    const int eb = (NE + 255) / 256;

    zero_k<<<(SCAN_N + 255) / 256, 256, 0, stream>>>((float*)cnt, SCAN_N);
    zero_k<<<(65792 + 255) / 256, 256, 0, stream>>>(G, 65792);   // G + cs

    // weight packs (once per call)
    packmat_k<<<512, 256, 0, stream>>>(c1_w1, W1p, 256 * 512);
    packmat_k<<<512, 256, 0, stream>>>(c1_w2, W2p, 512 * 256);
    packmat_k<<<256, 256, 0, stream>>>(c2_w1, W3p, 256 * 256);
    packmat_k<<<256, 256, 0, stream>>>(c2_w2, W4p, 256 * 256);

    atom_embed_k<<<NN / 4, 256, 0, stream>>>(x, atom_emb, Hh, Hl);

    // CSR build (conv-invariant)
    hist_k<<<eb, 256, 0, stream>>>(ei, cnt);
    scan1_k<<<SCAN_B, 256, 0, stream>>>(cnt, bsum);
    scan2_k<<<1, 512, 0, stream>>>(bsum, boff);
    scan3_k<<<SCAN_B, 256, 0, stream>>>(cnt, boff, rs, cursor);
    scatter_k<<<eb, 256, 0, stream>>>(ei, ea, cursor, meta);

    // ================= conv1 =================
    bcomb_k<<<1000, 256, 0, stream>>>(bond1, bcomb);
    gather_full_k<<<NN / 4, 256, 0, stream>>>(Hh, Hl, bcomb, rs, meta, Zh, Zl);
    gram_mfma_k<<<4 * NGCH, 256, 0, stream>>>(Zh, Zl, G);
    colsum_k<<<SCAN_B, 256, 0, stream>>>(Zh, Zl, cs);
    bnprep_k<<<512, 256, 0, stream>>>(G, cs, c1_w1, c1_b1, c1_g, c1_be, scl, shf, 512);
    for (int r0 = 0; r0 < NN; r0 += strip) {
        int Ms = (NN - r0 < strip) ? NN - r0 : strip;
        int mt = (Ms + 127) / 128;
        gemm_mfma_k<2, true, false><<<mt * 4, 256, 0, stream>>>(
            Zh + (size_t)r0 * DD, Zl + (size_t)r0 * DD, W1p, c1_b1,
            ysh, nullptr, Ms, 512, 256, scl, shf);
        gemm_mfma_k<1, false, true><<<mt * 2, 256, 0, stream>>>(
            ysh, nullptr, W2p, c1_b2,
            Hh + (size_t)r0 * DD, Hl + (size_t)r0 * DD, Ms, 256, 512, nullptr, nullptr);
    }

    // ================= conv2 =================
    zero_k<<<(65792 + 255) / 256, 256, 0, stream>>>(G, 65792);
    bcomb_k<<<1000, 256, 0, stream>>>(bond2, bcomb);
    gather_full_k<<<NN / 4, 256, 0, stream>>>(Hh, Hl, bcomb, rs, meta, Zh, Zl);
    gram_mfma_k<<<4 * NGCH, 256, 0, stream>>>(Zh, Zl, G);
    colsum_k<<<SCAN_B, 256, 0, stream>>>(Zh, Zl, cs);
    bnprep_k<<<256, 256, 0, stream>>>(G, cs, c2_w1, c2_b1, c2_g, c2_be, scl, shf, 256);
    for (int r0 = 0; r0 < NN; r0 += strip) {
        int Ms = (NN - r0 < strip) ? NN - r0 : strip;
        int mt = (Ms + 127) / 128;
        gemm_mfma_k<2, true, false><<<mt * 2, 256, 0, stream>>>(
            Zh + (size_t)r0 * DD, Zl + (size_t)r0 * DD, W3p, c2_b1,
            ysh, nullptr, Ms, 256, 256, scl, shf);
        gemm_mfma_k<1, false, true><<<mt * 2, 256, 0, stream>>>(
            ysh, nullptr, W4p, c2_b2,
            Hh + (size_t)r0 * DD, Hl + (size_t)r0 * DD, Ms, 256, 256, nullptr, nullptr);
    }

    // ---- pool ----
    pool_k<<<NG, 256, 0, stream>>>(Hh, Hl, batch, out);
}